// Round 4
// baseline (10492.887 us; speedup 1.0000x reference)
//
#include <hip/hip_runtime.h>
#include <hip/hip_bf16.h>

#define NN 80000       // nodes
#define NE 160000      // edges (both directions)
#define HALF 80000
#define HID 300
#define NG 1600

// ---------------- storage helpers: fp32 math, optional bf16 storage tier ----------------
__device__ __forceinline__ float bf2f_us(unsigned short u) {
    return __uint_as_float(((unsigned int)u) << 16);
}
__device__ __forceinline__ unsigned short f2bf_us(float f) {
    unsigned int u = __float_as_uint(f);
    u += 0x7fff + ((u >> 16) & 1);   // round-to-nearest-even
    return (unsigned short)(u >> 16);
}
__device__ __forceinline__ float ld1(const float* p) { return *p; }
__device__ __forceinline__ float ld1(const unsigned short* p) { return bf2f_us(*p); }
__device__ __forceinline__ void st1(float* p, float v) { *p = v; }
__device__ __forceinline__ void st1(unsigned short* p, float v) { *p = f2bf_us(v); }
__device__ __forceinline__ float4 ld4(const float* p) { return *(const float4*)p; }
__device__ __forceinline__ float4 ld4(const unsigned short* p) {
    ushort4 u = *(const ushort4*)p;
    return make_float4(bf2f_us(u.x), bf2f_us(u.y), bf2f_us(u.z), bf2f_us(u.w));
}
__device__ __forceinline__ void st4(float* p, float4 v) { *(float4*)p = v; }
__device__ __forceinline__ void st4(unsigned short* p, float4 v) {
    ushort4 u; u.x = f2bf_us(v.x); u.y = f2bf_us(v.y); u.z = f2bf_us(v.z); u.w = f2bf_us(v.w);
    *(ushort4*)p = u;
}
__device__ __forceinline__ int clampi(int v, int lo, int hi) {
    return v < lo ? lo : (v > hi ? hi : v);
}

// ---------------- zero-fill kernels ----------------
__global__ void k_zerof(float* __restrict__ p, int n) {
    int i = blockIdx.x * 256 + threadIdx.x; if (i < n) p[i] = 0.f;
}
__global__ void k_zeroi(int* __restrict__ p, int n) {
    int i = blockIdx.x * 256 + threadIdx.x; if (i < n) p[i] = 0;
}

// ---------------- weight pad: K x 300 fp32 -> KP x 300 fp32 (rows K..KP zero) ----------------
__global__ void k_wpad(const float* __restrict__ in, float* __restrict__ out, int K, int KP) {
    int idx = blockIdx.x * 256 + threadIdx.x;
    if (idx >= KP * 300) return;
    int k = idx / 300;
    int c = idx - k * 300;
    out[idx] = (k < K) ? in[k * 300 + c] : 0.f;
}

// ---------------- CSR build (incoming edges per node, keyed by dst) ----------------
__global__ void k_hist(const int* __restrict__ srcH, const int* __restrict__ dstH, int* __restrict__ deg) {
    int e = blockIdx.x * 256 + threadIdx.x;
    if (e >= NE) return;
    int d = (e < HALF) ? dstH[e] : srcH[e - HALF];
    d = clampi(d, 0, NN - 1);
    atomicAdd(&deg[d], 1);
}
__global__ void k_histg(const int* __restrict__ batch, int* __restrict__ degg) {
    int n = blockIdx.x * 256 + threadIdx.x;
    if (n >= NN) return;
    atomicAdd(&degg[clampi(batch[n], 0, NG - 1)], 1);
}
// generic 1-block scan: deg[0..n) -> exclusive prefix in start[0..n], start[n]=total; cursor copy
__global__ __launch_bounds__(1024) void k_scan_n(const int* __restrict__ deg, int* __restrict__ start,
                                                 int* __restrict__ cursor, int n) {
    __shared__ int part[1024];
    const int t = threadIdx.x;
    const int CH = (n + 1023) / 1024;
    int lo = t * CH;
    int hi = lo + CH; if (hi > n) hi = n;
    int s = 0;
    for (int i = lo; i < hi; ++i) s += deg[i];
    part[t] = s;
    __syncthreads();
    for (int off = 1; off < 1024; off <<= 1) {
        int v = 0;
        if (t >= off) v = part[t - off];
        __syncthreads();
        part[t] += v;
        __syncthreads();
    }
    int run = part[t] - s;  // exclusive prefix
    for (int i = lo; i < hi; ++i) {
        start[i] = run;
        if (cursor) cursor[i] = run;
        run += deg[i];
    }
    if (t == 1023) start[n] = run;
}
__global__ void k_fill(const int* __restrict__ srcH, const int* __restrict__ dstH,
                       int* __restrict__ cursor, int* __restrict__ elist) {
    int e = blockIdx.x * 256 + threadIdx.x;
    if (e >= NE) return;
    int d = (e < HALF) ? dstH[e] : srcH[e - HALF];
    d = clampi(d, 0, NN - 1);
    int pos = atomicAdd(&cursor[d], 1);
    if (pos >= 0 && pos < NE) elist[pos] = e;
}

// ---------------- segment sum v2: thread per (node, col-quad), float4 ----------------
template <typename TH, typename TI>
__global__ __launch_bounds__(256) void k_segsum2(const TH* __restrict__ h, const int* __restrict__ elist,
                                                 const int* __restrict__ start, TI* __restrict__ inc) {
    int t = blockIdx.x * 256 + threadIdx.x;
    if (t >= NN * 75) return;
    int n = t / 75, q = t - n * 75;
    int lo = clampi(start[n], 0, NE), hi = clampi(start[n + 1], 0, NE);
    float4 acc = make_float4(0.f, 0.f, 0.f, 0.f);
    for (int j = lo; j < hi; ++j) {
        int e = clampi(elist[j], 0, NE - 1);
        float4 v = ld4(&h[e * 300 + q * 4]);
        acc.x += v.x; acc.y += v.y; acc.z += v.z; acc.w += v.w;
    }
    st4(&inc[n * 300 + q * 4], acc);
}

// ---------------- lin GEMM (32-row): h[e] = relu(concat(node_in[src[e]], ea[e]) @ W + b) ----------------
template <int NID, typename TN, typename TH>
__global__ __launch_bounds__(320) void k_lin(const TN* __restrict__ node_in,
                                             const float* __restrict__ ea,
                                             const int* __restrict__ srcH, const int* __restrict__ dstH,
                                             const float* __restrict__ W, const float* __restrict__ bias,
                                             TH* __restrict__ h) {
    constexpr int K = NID + 14;
    constexpr int KP = (K + 3) & ~3;
    __shared__ float As[32][KP];
    __shared__ int ssrc[32];
    const int tid = threadIdx.x;
    const int e0 = blockIdx.x * 32;
    if (tid < 32) {
        int e = e0 + tid;
        int s = (e < HALF) ? srcH[e] : dstH[e - HALF];
        ssrc[tid] = clampi(s, 0, NN - 1);
    }
    __syncthreads();
    for (int idx = tid; idx < 32 * KP; idx += 320) {
        int r = idx / KP, k = idx - r * KP;
        float v;
        if (k < NID)       v = ld1(&node_in[ssrc[r] * NID + k]);
        else if (k < K)    v = ea[(e0 + r) * 14 + (k - NID)];
        else               v = 0.f;
        As[r][k] = v;
    }
    __syncthreads();
    if (tid >= 300) return;
    const int cq = tid % 75, rg = tid / 75;
    const int c0 = cq * 4, r0 = rg * 8;
    float acc[8][4];
    {
        float4 bv = *(const float4*)&bias[c0];
        for (int r = 0; r < 8; ++r) { acc[r][0] = bv.x; acc[r][1] = bv.y; acc[r][2] = bv.z; acc[r][3] = bv.w; }
    }
    // W register double-buffer: load k+4 before consuming k
    float4 w0 = *(const float4*)&W[0 * 300 + c0];
    float4 w1 = *(const float4*)&W[1 * 300 + c0];
    float4 w2 = *(const float4*)&W[2 * 300 + c0];
    float4 w3 = *(const float4*)&W[3 * 300 + c0];
    for (int k = 0; k < KP; k += 4) {
        int kn = (k + 4 < KP) ? k + 4 : k;
        float4 n0 = *(const float4*)&W[(kn + 0) * 300 + c0];
        float4 n1 = *(const float4*)&W[(kn + 1) * 300 + c0];
        float4 n2 = *(const float4*)&W[(kn + 2) * 300 + c0];
        float4 n3 = *(const float4*)&W[(kn + 3) * 300 + c0];
        #pragma unroll
        for (int r = 0; r < 8; ++r) {
            float4 ar = *(const float4*)&As[r0 + r][k];
            acc[r][0] += ar.x * w0.x + ar.y * w1.x + ar.z * w2.x + ar.w * w3.x;
            acc[r][1] += ar.x * w0.y + ar.y * w1.y + ar.z * w2.y + ar.w * w3.y;
            acc[r][2] += ar.x * w0.z + ar.y * w1.z + ar.z * w2.z + ar.w * w3.z;
            acc[r][3] += ar.x * w0.w + ar.y * w1.w + ar.z * w2.w + ar.w * w3.w;
        }
        w0 = n0; w1 = n1; w2 = n2; w3 = n3;
    }
    for (int r = 0; r < 8; ++r) {
        float4 o;
        o.x = fmaxf(acc[r][0], 0.f); o.y = fmaxf(acc[r][1], 0.f);
        o.z = fmaxf(acc[r][2], 0.f); o.w = fmaxf(acc[r][3], 0.f);
        st4(&h[(e0 + r0 + r) * 300 + c0], o);
    }
}

// ---------------- mp GEMM (in-place, pair-tiled):
// h[e] = relu(h[e] + (inc[src[e]] - h[rev(e)]) @ W + b)  for 32 rows = 16 pairs ----------------
template <typename TH, typename TI>
__global__ __launch_bounds__(320) void k_mp(TH* __restrict__ h, const TI* __restrict__ inc,
                                            const int* __restrict__ srcH, const int* __restrict__ dstH,
                                            const float* __restrict__ W, const float* __restrict__ bias) {
    __shared__ float Hs[32][300];   // becomes A-tile after in-place transform
    __shared__ int ssrc[32];
    const int tid = threadIdx.x;
    const int p0 = blockIdx.x * 16;
    if (tid < 32) {
        int r = tid;
        int e = (r < 16) ? (p0 + r) : (p0 + r - 16 + HALF);
        int s = (e < HALF) ? srcH[e] : dstH[e - HALF];
        ssrc[r] = clampi(s, 0, NN - 1);
    }
    for (int idx = tid; idx < 32 * 75; idx += 320) {
        int r = idx / 75, q = idx - r * 75;
        int e = (r < 16) ? (p0 + r) : (p0 + r - 16 + HALF);
        *(float4*)&Hs[r][q * 4] = ld4(&h[e * 300 + q * 4]);
    }
    __syncthreads();
    const int cq = tid % 75, rg = tid / 75;   // rg in 0..3 for tid<300
    const int c0 = cq * 4, r0 = rg * 8;
    float hval[8][4];
    if (tid < 300) {
        #pragma unroll
        for (int r = 0; r < 8; ++r) *(float4*)&hval[r][0] = *(const float4*)&Hs[r0 + r][c0];
    }
    __syncthreads();
    // in-place: Hs[r][k] <- inc[src[r]][k] - Hs[r^16][k]  (pairwise, race-free)
    for (int idx = tid; idx < 16 * 300; idx += 320) {
        int r = idx / 300, k = idx - r * 300;
        float h1 = Hs[r][k], h2 = Hs[r + 16][k];
        Hs[r][k]      = ld1(&inc[ssrc[r] * 300 + k])      - h2;
        Hs[r + 16][k] = ld1(&inc[ssrc[r + 16] * 300 + k]) - h1;
    }
    __syncthreads();
    if (tid >= 300) return;
    float acc[8][4];
    {
        float4 bv = *(const float4*)&bias[c0];
        for (int r = 0; r < 8; ++r) { acc[r][0] = bv.x; acc[r][1] = bv.y; acc[r][2] = bv.z; acc[r][3] = bv.w; }
    }
    float4 w0 = *(const float4*)&W[0 * 300 + c0];
    float4 w1 = *(const float4*)&W[1 * 300 + c0];
    float4 w2 = *(const float4*)&W[2 * 300 + c0];
    float4 w3 = *(const float4*)&W[3 * 300 + c0];
    for (int k = 0; k < 300; k += 4) {
        int kn = (k + 4 < 300) ? k + 4 : k;
        float4 n0 = *(const float4*)&W[(kn + 0) * 300 + c0];
        float4 n1 = *(const float4*)&W[(kn + 1) * 300 + c0];
        float4 n2 = *(const float4*)&W[(kn + 2) * 300 + c0];
        float4 n3 = *(const float4*)&W[(kn + 3) * 300 + c0];
        #pragma unroll
        for (int r = 0; r < 8; ++r) {
            float4 ar = *(const float4*)&Hs[r0 + r][k];
            acc[r][0] += ar.x * w0.x + ar.y * w1.x + ar.z * w2.x + ar.w * w3.x;
            acc[r][1] += ar.x * w0.y + ar.y * w1.y + ar.z * w2.y + ar.w * w3.y;
            acc[r][2] += ar.x * w0.z + ar.y * w1.z + ar.z * w2.z + ar.w * w3.z;
            acc[r][3] += ar.x * w0.w + ar.y * w1.w + ar.z * w2.w + ar.w * w3.w;
        }
        w0 = n0; w1 = n1; w2 = n2; w3 = n3;
    }
    #pragma unroll
    for (int r = 0; r < 8; ++r) {
        int rr = r0 + r;
        int e = (rr < 16) ? (p0 + rr) : (p0 + rr - 16 + HALF);
        float4 o;
        o.x = fmaxf(hval[r][0] + acc[r][0], 0.f);
        o.y = fmaxf(hval[r][1] + acc[r][1], 0.f);
        o.z = fmaxf(hval[r][2] + acc[r][2], 0.f);
        o.w = fmaxf(hval[r][3] + acc[r][3], 0.f);
        st4(&h[e * 300 + c0], o);
    }
}

// ---------------- au GEMM: rows[n] = (relu?)(concat(node_in[n], inc[n]) @ W + b) ----------------
template <int NID, typename TN, typename TI, typename TS, bool RELU>
__global__ __launch_bounds__(320) void k_au(const TN* __restrict__ node_in, const TI* __restrict__ inc,
                                            const float* __restrict__ W, const float* __restrict__ bias,
                                            TS* __restrict__ out_rows) {
    constexpr int K = NID + HID;         // 433 or 600
    constexpr int KP = (K + 3) & ~3;     // 436 or 600
    __shared__ float As[16][KP];
    const int tid = threadIdx.x;
    const int n0 = blockIdx.x * 16;
    for (int idx = tid; idx < 16 * KP; idx += 320) {
        int r = idx / KP, k = idx - r * KP;
        int n = n0 + r;
        float v;
        if (k < NID)      v = ld1(&node_in[n * NID + k]);
        else if (k < K)   v = ld1(&inc[n * 300 + (k - NID)]);
        else              v = 0.f;
        As[r][k] = v;
    }
    __syncthreads();
    if (tid >= 300) return;
    const int cq = tid % 75, rg = tid / 75;
    const int c0 = cq * 4, r0 = rg * 4;
    float acc[4][4];
    {
        float4 bv = *(const float4*)&bias[c0];
        for (int r = 0; r < 4; ++r) { acc[r][0] = bv.x; acc[r][1] = bv.y; acc[r][2] = bv.z; acc[r][3] = bv.w; }
    }
    float4 w0 = *(const float4*)&W[0 * 300 + c0];
    float4 w1 = *(const float4*)&W[1 * 300 + c0];
    float4 w2 = *(const float4*)&W[2 * 300 + c0];
    float4 w3 = *(const float4*)&W[3 * 300 + c0];
    for (int k = 0; k < KP; k += 4) {
        int kn = (k + 4 < KP) ? k + 4 : k;
        float4 n0v = *(const float4*)&W[(kn + 0) * 300 + c0];
        float4 n1v = *(const float4*)&W[(kn + 1) * 300 + c0];
        float4 n2v = *(const float4*)&W[(kn + 2) * 300 + c0];
        float4 n3v = *(const float4*)&W[(kn + 3) * 300 + c0];
        #pragma unroll
        for (int r = 0; r < 4; ++r) {
            float4 ar = *(const float4*)&As[r0 + r][k];
            acc[r][0] += ar.x * w0.x + ar.y * w1.x + ar.z * w2.x + ar.w * w3.x;
            acc[r][1] += ar.x * w0.y + ar.y * w1.y + ar.z * w2.y + ar.w * w3.y;
            acc[r][2] += ar.x * w0.z + ar.y * w1.z + ar.z * w2.z + ar.w * w3.z;
            acc[r][3] += ar.x * w0.w + ar.y * w1.w + ar.z * w2.w + ar.w * w3.w;
        }
        w0 = n0v; w1 = n1v; w2 = n2v; w3 = n3v;
    }
    for (int r = 0; r < 4; ++r) {
        float4 o;
        if (RELU) {
            o.x = fmaxf(acc[r][0], 0.f); o.y = fmaxf(acc[r][1], 0.f);
            o.z = fmaxf(acc[r][2], 0.f); o.w = fmaxf(acc[r][3], 0.f);
        } else {
            o.x = acc[r][0]; o.y = acc[r][1]; o.z = acc[r][2]; o.w = acc[r][3];
        }
        st4(&out_rows[(n0 + r0 + r) * 300 + c0], o);
    }
}

// ---------------- pooling: out_g[g] = sum_{n in graph g} rows[n]*wat[n] / max(cnt,1) ----------------
__global__ __launch_bounds__(320) void k_pool(const float* __restrict__ rows, const float* __restrict__ wat,
                                              const int* __restrict__ gs, float* __restrict__ outg) {
    int g = blockIdx.x, c = threadIdx.x;
    if (c >= 300) return;
    int lo = clampi(gs[g], 0, NN), hi = clampi(gs[g + 1], 0, NN);
    float acc = 0.f;
    for (int n = lo; n < hi; ++n)
        acc += rows[n * 300 + c] * wat[n];
    float cn = fmaxf((float)(hi - lo), 1.f);
    outg[g * 300 + c] = acc / cn;
}

// ---------------- final: z = mu_g + exp(0.5*lv_g) * eps ----------------
__global__ __launch_bounds__(320) void k_final(const float* __restrict__ mu_g, const float* __restrict__ lv_g,
                                               const float* __restrict__ eps, float* __restrict__ out) {
    int g = blockIdx.x, c = threadIdx.x;
    if (c >= 300) return;
    float z = mu_g[g * 300 + c] + expf(0.5f * lv_g[g * 300 + c]) * eps[g * 300 + c];
    out[g * 300 + c] = z;
}

// ---------------- host-side pipeline ----------------
struct Ctx {
    const float *x, *ea, *wat, *eps;
    const int *srcH, *dstH, *batch;
    const float *w_t_lin, *b_t_lin, *w_t_mp, *b_t_mp, *w_t_au, *b_t_au;
    const float *w_mu_lin, *b_mu_lin, *w_mu_mp, *b_mu_mp, *w_mu_au, *b_mu_au;
    const float *w_lv_lin, *b_lv_lin, *w_lv_mp, *b_lv_mp, *w_lv_au, *b_lv_au;
    float *mu_g, *lv_g;
    int *startA, *elist, *gs;
    hipStream_t stream;
};

template <typename TH, typename TI, typename TS>
static void run_pipeline(const Ctx& c, TH* h, TI* inc, TS* sh, float* rows) {
    hipStream_t stream = c.stream;
    const int SSG = (NN * 75 + 255) / 256;
    // ---- conv 1 (shared), node_in = x (fp32, 133) ----
    k_lin<133, float, TH><<<NE / 32, 320, 0, stream>>>(c.x, c.ea, c.srcH, c.dstH, c.w_t_lin, c.b_t_lin, h);
    for (int i = 0; i < 3; ++i) {
        k_segsum2<TH, TI><<<SSG, 256, 0, stream>>>(h, c.elist, c.startA, inc);
        k_mp<TH, TI><<<HALF / 16, 320, 0, stream>>>(h, inc, c.srcH, c.dstH, c.w_t_mp + i * 90000, c.b_t_mp + i * 300);
    }
    k_segsum2<TH, TI><<<SSG, 256, 0, stream>>>(h, c.elist, c.startA, inc);
    k_au<133, float, TI, TS, true><<<NN / 16, 320, 0, stream>>>(c.x, inc, c.w_t_au, c.b_t_au, sh);

    // ---- conv mu, node_in = sh (300) ----
    k_lin<300, TS, TH><<<NE / 32, 320, 0, stream>>>(sh, c.ea, c.srcH, c.dstH, c.w_mu_lin, c.b_mu_lin, h);
    for (int i = 0; i < 3; ++i) {
        k_segsum2<TH, TI><<<SSG, 256, 0, stream>>>(h, c.elist, c.startA, inc);
        k_mp<TH, TI><<<HALF / 16, 320, 0, stream>>>(h, inc, c.srcH, c.dstH, c.w_mu_mp + i * 90000, c.b_mu_mp + i * 300);
    }
    k_segsum2<TH, TI><<<SSG, 256, 0, stream>>>(h, c.elist, c.startA, inc);
    // h is dead now -> reuse as fp32 rows buffer
    k_au<300, TS, TI, float, false><<<NN / 16, 320, 0, stream>>>(sh, inc, c.w_mu_au, c.b_mu_au, rows);
    k_pool<<<NG, 320, 0, stream>>>(rows, c.wat, c.gs, c.mu_g);

    // ---- conv lv ----
    k_lin<300, TS, TH><<<NE / 32, 320, 0, stream>>>(sh, c.ea, c.srcH, c.dstH, c.w_lv_lin, c.b_lv_lin, h);
    for (int i = 0; i < 3; ++i) {
        k_segsum2<TH, TI><<<SSG, 256, 0, stream>>>(h, c.elist, c.startA, inc);
        k_mp<TH, TI><<<HALF / 16, 320, 0, stream>>>(h, inc, c.srcH, c.dstH, c.w_lv_mp + i * 90000, c.b_lv_mp + i * 300);
    }
    k_segsum2<TH, TI><<<SSG, 256, 0, stream>>>(h, c.elist, c.startA, inc);
    k_au<300, TS, TI, float, false><<<NN / 16, 320, 0, stream>>>(sh, inc, c.w_lv_au, c.b_lv_au, rows);
    k_pool<<<NG, 320, 0, stream>>>(rows, c.wat, c.gs, c.lv_g);
}

extern "C" void kernel_launch(void* const* d_in, const int* in_sizes, int n_in,
                              void* d_out, int out_size, void* d_ws, size_t ws_size,
                              hipStream_t stream) {
    float* outp = (float*)d_out;

    // tier selection by available workspace (constant across calls -> graph-safe)
    const size_t T0 = 392000000ull;   // all-fp32 h/inc/sh
    const size_t T1 = 296000000ull;   // h fp32, inc/sh bf16 storage
    const size_t T2 = 200000000ull;   // all bf16 storage
    int tier = (ws_size >= T0) ? 0 : (ws_size >= T1) ? 1 : (ws_size >= T2) ? 2 : 3;
    if (tier == 3) {
        k_zerof<<<(out_size + 255) / 256, 256, 0, stream>>>(outp, out_size);
        return;
    }

    Ctx c;
    c.x   = (const float*)d_in[0];
    c.ea  = (const float*)d_in[1];
    c.wat = (const float*)d_in[2];
    c.eps = (const float*)d_in[3];
    c.srcH  = (const int*)d_in[4];
    c.dstH  = (const int*)d_in[5];
    c.batch = (const int*)d_in[6];
    const float* w_t_lin_raw  = (const float*)d_in[7];
    c.b_t_lin  = (const float*)d_in[8];
    c.w_t_mp   = (const float*)d_in[9];
    c.b_t_mp   = (const float*)d_in[10];
    const float* w_t_au_raw   = (const float*)d_in[11];
    c.b_t_au   = (const float*)d_in[12];
    const float* w_mu_lin_raw = (const float*)d_in[13];
    c.b_mu_lin = (const float*)d_in[14];
    c.w_mu_mp  = (const float*)d_in[15];
    c.b_mu_mp  = (const float*)d_in[16];
    c.w_mu_au  = (const float*)d_in[17];   // 600 rows, K%4==0: use directly
    c.b_mu_au  = (const float*)d_in[18];
    const float* w_lv_lin_raw = (const float*)d_in[19];
    c.b_lv_lin = (const float*)d_in[20];
    c.w_lv_mp  = (const float*)d_in[21];
    c.b_lv_mp  = (const float*)d_in[22];
    c.w_lv_au  = (const float*)d_in[23];   // 600 rows
    c.b_lv_au  = (const float*)d_in[24];
    c.stream = stream;

    // ---- workspace carve ----
    char* p = (char*)d_ws;
    auto alloc = [&](size_t nbytes) { char* q = p; p += (nbytes + 255) & ~(size_t)255; return q; };
    const size_t thB = (tier == 2) ? 2 : 4;
    const size_t tiB = (tier >= 1) ? 2 : 4;
    const size_t tsB = (tier >= 1) ? 2 : 4;
    void* h_raw   = alloc((size_t)NE * 300 * thB);   // also reused as fp32 rows buffer (NN*300*4 <= NE*300*2)
    void* inc_raw = alloc((size_t)NN * 300 * tiB);
    void* sh_raw  = alloc((size_t)NN * 300 * tsB);
    float* w_t_lin_p  = (float*)alloc(148 * 300 * 4);   // pad 147 -> 148
    float* w_t_au_p   = (float*)alloc(436 * 300 * 4);   // pad 433 -> 436
    float* w_mu_lin_p = (float*)alloc(316 * 300 * 4);   // pad 314 -> 316
    float* w_lv_lin_p = (float*)alloc(316 * 300 * 4);   // pad 314 -> 316
    c.mu_g = (float*)alloc((size_t)NG * 300 * 4);
    c.lv_g = (float*)alloc((size_t)NG * 300 * 4);
    int* deg    = (int*)alloc(NN * 4);
    c.startA    = (int*)alloc((NN + 1) * 4);
    int* cursor = (int*)alloc(NN * 4);
    c.elist     = (int*)alloc(NE * 4);
    int* degg   = (int*)alloc(NG * 4);
    c.gs        = (int*)alloc((NG + 1) * 4);

    // ---- pad the K%4 != 0 weights ----
    auto wp = [&](const float* in, float* out, int K, int KP) {
        k_wpad<<<(KP * 300 + 255) / 256, 256, 0, stream>>>(in, out, K, KP);
    };
    wp(w_t_lin_raw,  w_t_lin_p,  147, 148);  c.w_t_lin  = w_t_lin_p;
    wp(w_t_au_raw,   w_t_au_p,   433, 436);  c.w_t_au   = w_t_au_p;
    wp(w_mu_lin_raw, w_mu_lin_p, 314, 316);  c.w_mu_lin = w_mu_lin_p;
    wp(w_lv_lin_raw, w_lv_lin_p, 314, 316);  c.w_lv_lin = w_lv_lin_p;

    // ---- CSR (incoming edges by dst) ----
    k_zeroi<<<(NN + 255) / 256, 256, 0, stream>>>(deg, NN);
    k_hist<<<(NE + 255) / 256, 256, 0, stream>>>(c.srcH, c.dstH, deg);
    k_scan_n<<<1, 1024, 0, stream>>>(deg, c.startA, cursor, NN);
    k_fill<<<(NE + 255) / 256, 256, 0, stream>>>(c.srcH, c.dstH, cursor, c.elist);

    // ---- graph-CSR over sorted batch (for pooling) ----
    k_zeroi<<<(NG + 255) / 256, 256, 0, stream>>>(degg, NG);
    k_histg<<<(NN + 255) / 256, 256, 0, stream>>>(c.batch, degg);
    k_scan_n<<<1, 1024, 0, stream>>>(degg, c.gs, (int*)nullptr, NG);

    // ---- pipeline ----
    if (tier == 0)
        run_pipeline<float, float, float>(c, (float*)h_raw, (float*)inc_raw, (float*)sh_raw, (float*)h_raw);
    else if (tier == 1)
        run_pipeline<float, unsigned short, unsigned short>(c, (float*)h_raw, (unsigned short*)inc_raw, (unsigned short*)sh_raw, (float*)h_raw);
    else
        run_pipeline<unsigned short, unsigned short, unsigned short>(c, (unsigned short*)h_raw, (unsigned short*)inc_raw, (unsigned short*)sh_raw, (float*)h_raw);

    // ---- reparam ----
    k_final<<<NG, 320, 0, stream>>>(c.mu_g, c.lv_g, c.eps, outp);
}

// Round 6
// 6412.395 us; speedup vs baseline: 1.6363x; 1.6363x over previous
//
#include <hip/hip_runtime.h>
#include <hip/hip_bf16.h>

#define NN 80000       // nodes
#define NE 160000      // edges (both directions)
#define HALF 80000
#define HID 300
#define NG 1600

typedef __attribute__((ext_vector_type(8))) short bf16x8v;
typedef __attribute__((ext_vector_type(4))) float f32x4v;

// ---------------- helpers ----------------
__device__ __forceinline__ float bf2f_us(unsigned short u) {
    return __uint_as_float(((unsigned int)u) << 16);
}
__device__ __forceinline__ unsigned short f2bf_us(float f) {
    unsigned int u = __float_as_uint(f);
    u += 0x7fff + ((u >> 16) & 1);   // RNE
    return (unsigned short)(u >> 16);
}
__device__ __forceinline__ float ld1(const float* p) { return *p; }
__device__ __forceinline__ float ld1(const unsigned short* p) { return bf2f_us(*p); }
__device__ __forceinline__ void st1(float* p, float v) { *p = v; }
__device__ __forceinline__ void st1(unsigned short* p, float v) { *p = f2bf_us(v); }
__device__ __forceinline__ float4 ld4(const float* p) { return *(const float4*)p; }
__device__ __forceinline__ float4 ld4(const unsigned short* p) {
    ushort4 u = *(const ushort4*)p;
    return make_float4(bf2f_us(u.x), bf2f_us(u.y), bf2f_us(u.z), bf2f_us(u.w));
}
__device__ __forceinline__ void st4(float* p, float4 v) { *(float4*)p = v; }
__device__ __forceinline__ void st4(unsigned short* p, float4 v) {
    ushort4 u; u.x = f2bf_us(v.x); u.y = f2bf_us(v.y); u.z = f2bf_us(v.z); u.w = f2bf_us(v.w);
    *(ushort4*)p = u;
}
__device__ __forceinline__ int clampi(int v, int lo, int hi) {
    return v < lo ? lo : (v > hi ? hi : v);
}

// ---------------- zero-fill ----------------
__global__ void k_zerof(float* __restrict__ p, int n) {
    int i = blockIdx.x * 256 + threadIdx.x; if (i < n) p[i] = 0.f;
}
__global__ void k_zeroi(int* __restrict__ p, int n) {
    int i = blockIdx.x * 256 + threadIdx.x; if (i < n) p[i] = 0;
}

// ---------------- weight pad: K x 300 -> KP x 300 (rows K..KP zero) ----------------
__global__ void k_wpad(const float* __restrict__ in, float* __restrict__ out, int K, int KP) {
    int idx = blockIdx.x * 256 + threadIdx.x;
    if (idx >= KP * 300) return;
    int k = idx / 300;
    int c = idx - k * 300;
    out[idx] = (k < K) ? in[k * 300 + c] : 0.f;
}

// ---------------- W split+swizzle for MFMA: (3,300,300) fp32 -> hi/lo bf16 fragment order ----
// per layer l: tiles (kt<10, ct<19); lane holds B[k=kt*32+quad*8+j][n=ct*16+(lane&15)], j=0..7
__global__ void k_wsplit(const float* __restrict__ W3, unsigned short* __restrict__ whi,
                         unsigned short* __restrict__ wlo) {
    int idx = blockIdx.x * 256 + threadIdx.x;
    if (idx >= 3 * 190 * 64) return;
    int lane = idx & 63;
    int t = idx >> 6;                 // l*190 + kt*19 + ct
    int l = t / 190;
    int rem = t - l * 190;
    int kt = rem / 19, ct = rem - kt * 19;
    int quad = lane >> 4, cr = lane & 15;
    size_t obase = ((size_t)t * 64 + lane) * 8;
    for (int j = 0; j < 8; ++j) {
        int k = kt * 32 + quad * 8 + j;
        int n = ct * 16 + cr;
        float v = (k < 300 && n < 300) ? W3[l * 90000 + k * 300 + n] : 0.f;
        unsigned short hu = f2bf_us(v);
        unsigned short lu = f2bf_us(v - bf2f_us(hu));
        whi[obase + j] = hu;
        wlo[obase + j] = lu;
    }
}

// ---------------- CSR build ----------------
__global__ void k_hist(const int* __restrict__ srcH, const int* __restrict__ dstH, int* __restrict__ deg) {
    int e = blockIdx.x * 256 + threadIdx.x;
    if (e >= NE) return;
    int d = (e < HALF) ? dstH[e] : srcH[e - HALF];
    d = clampi(d, 0, NN - 1);
    atomicAdd(&deg[d], 1);
}
__global__ void k_histg(const int* __restrict__ batch, int* __restrict__ degg) {
    int n = blockIdx.x * 256 + threadIdx.x;
    if (n >= NN) return;
    atomicAdd(&degg[clampi(batch[n], 0, NG - 1)], 1);
}
// alias-safe scan (cursor may alias deg)
__global__ __launch_bounds__(1024) void k_scan_n(const int* __restrict__ deg, int* __restrict__ start,
                                                 int* cursor, int n) {
    __shared__ int part[1024];
    const int t = threadIdx.x;
    const int CH = (n + 1023) / 1024;
    int lo = t * CH;
    int hi = lo + CH; if (hi > n) hi = n;
    int s = 0;
    for (int i = lo; i < hi; ++i) s += deg[i];
    part[t] = s;
    __syncthreads();
    for (int off = 1; off < 1024; off <<= 1) {
        int v = 0;
        if (t >= off) v = part[t - off];
        __syncthreads();
        part[t] += v;
        __syncthreads();
    }
    int run = part[t] - s;
    for (int i = lo; i < hi; ++i) {
        int d = deg[i];
        start[i] = run;
        if (cursor) cursor[i] = run;
        run += d;
    }
    if (t == 1023) start[n] = run;
}
__global__ void k_fill(const int* __restrict__ srcH, const int* __restrict__ dstH,
                       int* __restrict__ cursor, int* __restrict__ elist) {
    int e = blockIdx.x * 256 + threadIdx.x;
    if (e >= NE) return;
    int d = (e < HALF) ? dstH[e] : srcH[e - HALF];
    d = clampi(d, 0, NN - 1);
    int pos = atomicAdd(&cursor[d], 1);
    if (pos >= 0 && pos < NE) elist[pos] = e;
}

// ---------------- segment sum: thread per (node, col-quad), float4 ----------------
template <typename TH, typename TI>
__global__ __launch_bounds__(256) void k_segsum2(const TH* __restrict__ h, const int* __restrict__ elist,
                                                 const int* __restrict__ start, TI* __restrict__ inc) {
    int t = blockIdx.x * 256 + threadIdx.x;
    if (t >= NN * 75) return;
    int n = t / 75, q = t - n * 75;
    int lo = clampi(start[n], 0, NE), hi = clampi(start[n + 1], 0, NE);
    float4 acc = make_float4(0.f, 0.f, 0.f, 0.f);
    for (int j = lo; j < hi; ++j) {
        int e = clampi(elist[j], 0, NE - 1);
        float4 v = ld4(&h[e * 300 + q * 4]);
        acc.x += v.x; acc.y += v.y; acc.z += v.z; acc.w += v.w;
    }
    st4(&inc[n * 300 + q * 4], acc);
}

// ---------------- lin GEMM (round-3 proven body) ----------------
template <int NID, typename TN, typename TH>
__global__ __launch_bounds__(320) void k_lin(const TN* __restrict__ node_in,
                                             const float* __restrict__ ea,
                                             const int* __restrict__ srcH, const int* __restrict__ dstH,
                                             const float* __restrict__ W, const float* __restrict__ bias,
                                             TH* __restrict__ h) {
    constexpr int K = NID + 14;
    constexpr int KP = (K + 3) & ~3;
    __shared__ float As[16][KP];
    __shared__ int ssrc[16];
    const int tid = threadIdx.x;
    const int e0 = blockIdx.x * 16;
    if (tid < 16) {
        int e = e0 + tid;
        int s = (e < HALF) ? srcH[e] : dstH[e - HALF];
        ssrc[tid] = clampi(s, 0, NN - 1);
    }
    __syncthreads();
    for (int idx = tid; idx < 16 * KP; idx += 320) {
        int r = idx / KP, k = idx - r * KP;
        float v;
        if (k < NID)       v = ld1(&node_in[ssrc[r] * NID + k]);
        else if (k < K)    v = ea[(e0 + r) * 14 + (k - NID)];
        else               v = 0.f;
        As[r][k] = v;
    }
    __syncthreads();
    if (tid >= 300) return;
    const int cq = tid % 75, rg = tid / 75;
    const int c0 = cq * 4, r0 = rg * 4;
    float acc[4][4];
    {
        float4 bv = *(const float4*)&bias[c0];
        for (int r = 0; r < 4; ++r) { acc[r][0] = bv.x; acc[r][1] = bv.y; acc[r][2] = bv.z; acc[r][3] = bv.w; }
    }
    for (int k = 0; k < KP; k += 4) {
        float a[4][4];
        #pragma unroll
        for (int r = 0; r < 4; ++r) *(float4*)&a[r][0] = *(const float4*)&As[r0 + r][k];
        #pragma unroll
        for (int kk = 0; kk < 4; ++kk) {
            const float4 wv = *(const float4*)&W[(k + kk) * 300 + c0];
            #pragma unroll
            for (int r = 0; r < 4; ++r) {
                acc[r][0] += a[r][kk] * wv.x; acc[r][1] += a[r][kk] * wv.y;
                acc[r][2] += a[r][kk] * wv.z; acc[r][3] += a[r][kk] * wv.w;
            }
        }
    }
    for (int r = 0; r < 4; ++r) {
        float4 o;
        o.x = fmaxf(acc[r][0], 0.f); o.y = fmaxf(acc[r][1], 0.f);
        o.z = fmaxf(acc[r][2], 0.f); o.w = fmaxf(acc[r][3], 0.f);
        st4(&h[(e0 + r0 + r) * 300 + c0], o);
    }
}

// ---------------- mp GEMM, MFMA split-bf16 ----------------
// h[e] = relu(h[e] + (inc[src[e]] - h[rev(e)]) @ W + b), 32 rows = 16 pairs / block
#define LDA 324
template <typename TH, typename TI>
__global__ __launch_bounds__(256, 3) void k_mp_mfma(
        TH* __restrict__ h, const TI* __restrict__ inc,
        const int* __restrict__ srcH, const int* __restrict__ dstH,
        const unsigned short* __restrict__ whi, const unsigned short* __restrict__ wlo,
        const float* __restrict__ bias) {
    __shared__ float Hs[32 * LDA];
    __shared__ int ssrc[32];
    const int tid = threadIdx.x;
    const int lane = tid & 63;
    const int wv = tid >> 6;                 // 0..3
    const int quad = lane >> 4, cr = lane & 15;
    const int p0 = blockIdx.x * 16;
    if (tid < 32) {
        int r = tid;
        int e = (r < 16) ? (p0 + r) : (p0 + r - 16 + HALF);
        int s = (e < HALF) ? srcH[e] : dstH[e - HALF];
        ssrc[r] = clampi(s, 0, NN - 1);
    }
    // stage h_old rows (zero pad cols [300,320))
    for (int idx = tid; idx < 32 * 80; idx += 256) {
        int r = idx / 80, q4 = idx - r * 80;
        int col = q4 * 4;
        float4 v = make_float4(0.f, 0.f, 0.f, 0.f);
        if (col < 300) {
            int e = (r < 16) ? (p0 + r) : (p0 + r - 16 + HALF);
            v = ld4(&h[(size_t)e * 300 + col]);
        }
        *(float4*)&Hs[r * LDA + col] = v;
    }
    __syncthreads();
    // C init: acc = h_old + bias   (wave -> row-tile rt, col-tiles c0t+2i)
    const int rt = wv & 1;
    const int c0t = wv >> 1;
    f32x4v acc[10];
    #pragma unroll
    for (int i = 0; i < 10; ++i) {
        int ct = c0t + 2 * i;
        f32x4v a = {0.f, 0.f, 0.f, 0.f};
        if (ct < 19) {
            int col = ct * 16 + cr;
            if (col < 300) {
                float b = bias[col];
                #pragma unroll
                for (int r = 0; r < 4; ++r)
                    a[r] = Hs[(rt * 16 + quad * 4 + r) * LDA + col] + b;
            }
        }
        acc[i] = a;
    }
    __syncthreads();
    // pairwise in-place transform: Hs[r] <- inc[src[r]] - Hs[r^16]
    for (int idx = tid; idx < 16 * 80; idx += 256) {
        int r = idx / 80, q4 = idx - r * 80;
        int col = q4 * 4;
        float4 a = *(const float4*)&Hs[r * LDA + col];
        float4 b = *(const float4*)&Hs[(r + 16) * LDA + col];
        float4 i1 = make_float4(0.f, 0.f, 0.f, 0.f), i2 = i1;
        if (col < 300) {
            i1 = ld4(&inc[(size_t)ssrc[r] * 300 + col]);
            i2 = ld4(&inc[(size_t)ssrc[r + 16] * 300 + col]);
        }
        *(float4*)&Hs[r * LDA + col]        = make_float4(i1.x - b.x, i1.y - b.y, i1.z - b.z, i1.w - b.w);
        *(float4*)&Hs[(r + 16) * LDA + col] = make_float4(i2.x - a.x, i2.y - a.y, i2.z - a.z, i2.w - a.w);
    }
    __syncthreads();
    // K loop: A split on the fly; D += Alo*Whi + Ahi*Wlo + Ahi*Whi
    for (int kt = 0; kt < 10; ++kt) {
        const float* ap = &Hs[(rt * 16 + cr) * LDA + kt * 32 + quad * 8];
        float4 v0 = *(const float4*)ap;
        float4 v1 = *(const float4*)(ap + 4);
        float vv[8] = {v0.x, v0.y, v0.z, v0.w, v1.x, v1.y, v1.z, v1.w};
        bf16x8v ahi, alo;
        #pragma unroll
        for (int j = 0; j < 8; ++j) {
            unsigned short hu = f2bf_us(vv[j]);
            ahi[j] = (short)hu;
            alo[j] = (short)f2bf_us(vv[j] - bf2f_us(hu));
        }
        #pragma unroll
        for (int i = 0; i < 10; ++i) {
            int ct = c0t + 2 * i;
            if (ct >= 19) break;
            size_t base = ((size_t)(kt * 19 + ct) * 64 + lane) * 8;
            bf16x8v bhi = *(const bf16x8v*)&whi[base];
            bf16x8v blo = *(const bf16x8v*)&wlo[base];
            acc[i] = __builtin_amdgcn_mfma_f32_16x16x32_bf16(alo, bhi, acc[i], 0, 0, 0);
            acc[i] = __builtin_amdgcn_mfma_f32_16x16x32_bf16(ahi, blo, acc[i], 0, 0, 0);
            acc[i] = __builtin_amdgcn_mfma_f32_16x16x32_bf16(ahi, bhi, acc[i], 0, 0, 0);
        }
    }
    // epilogue: relu + store (D layout: row = quad*4+r, col = lane&15)
    #pragma unroll
    for (int i = 0; i < 10; ++i) {
        int ct = c0t + 2 * i;
        if (ct >= 19) break;
        int col = ct * 16 + cr;
        if (col >= 300) continue;
        #pragma unroll
        for (int r = 0; r < 4; ++r) {
            int lrow = rt * 16 + quad * 4 + r;
            int e = (lrow < 16) ? (p0 + lrow) : (p0 + lrow - 16 + HALF);
            st1(&h[(size_t)e * 300 + col], fmaxf(acc[i][r], 0.f));
        }
    }
}

// ---------------- mp GEMM, vector fallback (round-3 proven body) ----------------
template <typename TH, typename TI>
__global__ __launch_bounds__(320) void k_mp(TH* __restrict__ h, const TI* __restrict__ inc,
                                            const int* __restrict__ srcH, const int* __restrict__ dstH,
                                            const float* __restrict__ W, const float* __restrict__ bias) {
    __shared__ float Hs[32][300];
    __shared__ int ssrc[32];
    const int tid = threadIdx.x;
    const int p0 = blockIdx.x * 16;
    if (tid < 32) {
        int r = tid;
        int e = (r < 16) ? (p0 + r) : (p0 + r - 16 + HALF);
        int s = (e < HALF) ? srcH[e] : dstH[e - HALF];
        ssrc[r] = clampi(s, 0, NN - 1);
    }
    for (int idx = tid; idx < 32 * 75; idx += 320) {
        int r = idx / 75, q = idx - r * 75;
        int e = (r < 16) ? (p0 + r) : (p0 + r - 16 + HALF);
        *(float4*)&Hs[r][q * 4] = ld4(&h[e * 300 + q * 4]);
    }
    __syncthreads();
    const int cq = tid % 75, rg = tid / 75;
    const int c0 = cq * 4, r0 = rg * 8;
    float hval[8][4];
    if (tid < 300) {
        #pragma unroll
        for (int r = 0; r < 8; ++r) *(float4*)&hval[r][0] = *(const float4*)&Hs[r0 + r][c0];
    }
    __syncthreads();
    for (int idx = tid; idx < 16 * 300; idx += 320) {
        int r = idx / 300, k = idx - r * 300;
        float h1 = Hs[r][k], h2 = Hs[r + 16][k];
        Hs[r][k]      = ld1(&inc[ssrc[r] * 300 + k])      - h2;
        Hs[r + 16][k] = ld1(&inc[ssrc[r + 16] * 300 + k]) - h1;
    }
    __syncthreads();
    if (tid >= 300) return;
    float acc[8][4];
    {
        float4 bv = *(const float4*)&bias[c0];
        for (int r = 0; r < 8; ++r) { acc[r][0] = bv.x; acc[r][1] = bv.y; acc[r][2] = bv.z; acc[r][3] = bv.w; }
    }
    for (int k = 0; k < 300; k += 4) {
        float a[8][4];
        #pragma unroll
        for (int r = 0; r < 8; ++r) *(float4*)&a[r][0] = *(const float4*)&Hs[r0 + r][k];
        #pragma unroll
        for (int kk = 0; kk < 4; ++kk) {
            const float4 wv = *(const float4*)&W[(k + kk) * 300 + c0];
            #pragma unroll
            for (int r = 0; r < 8; ++r) {
                acc[r][0] += a[r][kk] * wv.x; acc[r][1] += a[r][kk] * wv.y;
                acc[r][2] += a[r][kk] * wv.z; acc[r][3] += a[r][kk] * wv.w;
            }
        }
    }
    #pragma unroll
    for (int r = 0; r < 8; ++r) {
        int rr = r0 + r;
        int e = (rr < 16) ? (p0 + rr) : (p0 + rr - 16 + HALF);
        float4 o;
        o.x = fmaxf(hval[r][0] + acc[r][0], 0.f);
        o.y = fmaxf(hval[r][1] + acc[r][1], 0.f);
        o.z = fmaxf(hval[r][2] + acc[r][2], 0.f);
        o.w = fmaxf(hval[r][3] + acc[r][3], 0.f);
        st4(&h[e * 300 + c0], o);
    }
}

// ---------------- au GEMM (round-3 proven body, rows output) ----------------
template <int NID, typename TN, typename TI, typename TS, bool RELU>
__global__ __launch_bounds__(320) void k_au(const TN* __restrict__ node_in, const TI* __restrict__ inc,
                                            const float* __restrict__ W, const float* __restrict__ bias,
                                            TS* __restrict__ out_rows) {
    constexpr int K = NID + HID;
    constexpr int KP = (K + 3) & ~3;
    __shared__ float As[16][KP];
    const int tid = threadIdx.x;
    const int n0 = blockIdx.x * 16;
    for (int idx = tid; idx < 16 * KP; idx += 320) {
        int r = idx / KP, k = idx - r * KP;
        int n = n0 + r;
        float v;
        if (k < NID)      v = ld1(&node_in[n * NID + k]);
        else if (k < K)   v = ld1(&inc[n * 300 + (k - NID)]);
        else              v = 0.f;
        As[r][k] = v;
    }
    __syncthreads();
    if (tid >= 300) return;
    const int cq = tid % 75, rg = tid / 75;
    const int c0 = cq * 4, r0 = rg * 4;
    float acc[4][4];
    {
        float4 bv = *(const float4*)&bias[c0];
        for (int r = 0; r < 4; ++r) { acc[r][0] = bv.x; acc[r][1] = bv.y; acc[r][2] = bv.z; acc[r][3] = bv.w; }
    }
    for (int k = 0; k < KP; k += 4) {
        float a[4][4];
        #pragma unroll
        for (int r = 0; r < 4; ++r) *(float4*)&a[r][0] = *(const float4*)&As[r0 + r][k];
        #pragma unroll
        for (int kk = 0; kk < 4; ++kk) {
            const float4 wv = *(const float4*)&W[(k + kk) * 300 + c0];
            #pragma unroll
            for (int r = 0; r < 4; ++r) {
                acc[r][0] += a[r][kk] * wv.x; acc[r][1] += a[r][kk] * wv.y;
                acc[r][2] += a[r][kk] * wv.z; acc[r][3] += a[r][kk] * wv.w;
            }
        }
    }
    for (int r = 0; r < 4; ++r) {
        float4 o;
        if (RELU) {
            o.x = fmaxf(acc[r][0], 0.f); o.y = fmaxf(acc[r][1], 0.f);
            o.z = fmaxf(acc[r][2], 0.f); o.w = fmaxf(acc[r][3], 0.f);
        } else {
            o.x = acc[r][0]; o.y = acc[r][1]; o.z = acc[r][2]; o.w = acc[r][3];
        }
        st4(&out_rows[(n0 + r0 + r) * 300 + c0], o);
    }
}

// ---------------- pooling + reparam ----------------
__global__ __launch_bounds__(320) void k_pool(const float* __restrict__ rows, const float* __restrict__ wat,
                                              const int* __restrict__ gs, float* __restrict__ outg) {
    int g = blockIdx.x, c = threadIdx.x;
    if (c >= 300) return;
    int lo = clampi(gs[g], 0, NN), hi = clampi(gs[g + 1], 0, NN);
    float acc = 0.f;
    for (int n = lo; n < hi; ++n)
        acc += rows[n * 300 + c] * wat[n];
    float cn = fmaxf((float)(hi - lo), 1.f);
    outg[g * 300 + c] = acc / cn;
}
__global__ __launch_bounds__(320) void k_final(const float* __restrict__ mu_g, const float* __restrict__ lv_g,
                                               const float* __restrict__ eps, float* __restrict__ out) {
    int g = blockIdx.x, c = threadIdx.x;
    if (c >= 300) return;
    out[g * 300 + c] = mu_g[g * 300 + c] + expf(0.5f * lv_g[g * 300 + c]) * eps[g * 300 + c];
}

// ---------------- host ----------------
struct Ctx {
    const float *x, *ea, *wat, *eps;
    const int *srcH, *dstH, *batch;
    const float *w_t_lin, *b_t_lin, *w_t_mp, *b_t_mp, *w_t_au, *b_t_au;
    const float *w_mu_lin, *b_mu_lin, *w_mu_mp, *b_mu_mp, *w_mu_au, *b_mu_au;
    const float *w_lv_lin, *b_lv_lin, *w_lv_mp, *b_lv_mp, *w_lv_au, *b_lv_au;
    float *mu_g, *lv_g;
    int *startA, *elist, *gs;
    hipStream_t stream;
};

// primary: bf16 storage + MFMA mp; W tables re-split per conv into shared hi/lo buffers
static void run_mfma(const Ctx& c, unsigned short* h, unsigned short* inc, unsigned short* sh,
                     float* rows, unsigned short* wh, unsigned short* wl) {
    hipStream_t stream = c.stream;
    const int SSG = (NN * 75 + 255) / 256;
    const size_t LSTRIDE = (size_t)190 * 64 * 8;   // ushorts per layer
    const int WG = (3 * 190 * 64 + 255) / 256;
    // conv t
    k_wsplit<<<WG, 256, 0, stream>>>(c.w_t_mp, wh, wl);
    k_lin<133, float, unsigned short><<<NE / 16, 320, 0, stream>>>(c.x, c.ea, c.srcH, c.dstH, c.w_t_lin, c.b_t_lin, h);
    for (int i = 0; i < 3; ++i) {
        k_segsum2<unsigned short, unsigned short><<<SSG, 256, 0, stream>>>(h, c.elist, c.startA, inc);
        k_mp_mfma<unsigned short, unsigned short><<<HALF / 16, 256, 0, stream>>>(
            h, inc, c.srcH, c.dstH, wh + i * LSTRIDE, wl + i * LSTRIDE, c.b_t_mp + i * 300);
    }
    k_segsum2<unsigned short, unsigned short><<<SSG, 256, 0, stream>>>(h, c.elist, c.startA, inc);
    k_au<133, float, unsigned short, unsigned short, true><<<NN / 16, 320, 0, stream>>>(c.x, inc, c.w_t_au, c.b_t_au, sh);
    // conv mu
    k_wsplit<<<WG, 256, 0, stream>>>(c.w_mu_mp, wh, wl);
    k_lin<300, unsigned short, unsigned short><<<NE / 16, 320, 0, stream>>>(sh, c.ea, c.srcH, c.dstH, c.w_mu_lin, c.b_mu_lin, h);
    for (int i = 0; i < 3; ++i) {
        k_segsum2<unsigned short, unsigned short><<<SSG, 256, 0, stream>>>(h, c.elist, c.startA, inc);
        k_mp_mfma<unsigned short, unsigned short><<<HALF / 16, 256, 0, stream>>>(
            h, inc, c.srcH, c.dstH, wh + i * LSTRIDE, wl + i * LSTRIDE, c.b_mu_mp + i * 300);
    }
    k_segsum2<unsigned short, unsigned short><<<SSG, 256, 0, stream>>>(h, c.elist, c.startA, inc);
    k_au<300, unsigned short, unsigned short, float, false><<<NN / 16, 320, 0, stream>>>(sh, inc, c.w_mu_au, c.b_mu_au, rows);
    k_pool<<<NG, 320, 0, stream>>>(rows, c.wat, c.gs, c.mu_g);
    // conv lv
    k_wsplit<<<WG, 256, 0, stream>>>(c.w_lv_mp, wh, wl);
    k_lin<300, unsigned short, unsigned short><<<NE / 16, 320, 0, stream>>>(sh, c.ea, c.srcH, c.dstH, c.w_lv_lin, c.b_lv_lin, h);
    for (int i = 0; i < 3; ++i) {
        k_segsum2<unsigned short, unsigned short><<<SSG, 256, 0, stream>>>(h, c.elist, c.startA, inc);
        k_mp_mfma<unsigned short, unsigned short><<<HALF / 16, 256, 0, stream>>>(
            h, inc, c.srcH, c.dstH, wh + i * LSTRIDE, wl + i * LSTRIDE, c.b_lv_mp + i * 300);
    }
    k_segsum2<unsigned short, unsigned short><<<SSG, 256, 0, stream>>>(h, c.elist, c.startA, inc);
    k_au<300, unsigned short, unsigned short, float, false><<<NN / 16, 320, 0, stream>>>(sh, inc, c.w_lv_au, c.b_lv_au, rows);
    k_pool<<<NG, 320, 0, stream>>>(rows, c.wat, c.gs, c.lv_g);
}

// fallback: vector mp, all-bf16 storage (proven rounds 3/4)
static void run_vec(const Ctx& c, unsigned short* h, unsigned short* inc, unsigned short* sh, float* rows) {
    hipStream_t stream = c.stream;
    const int SSG = (NN * 75 + 255) / 256;
    k_lin<133, float, unsigned short><<<NE / 16, 320, 0, stream>>>(c.x, c.ea, c.srcH, c.dstH, c.w_t_lin, c.b_t_lin, h);
    for (int i = 0; i < 3; ++i) {
        k_segsum2<unsigned short, unsigned short><<<SSG, 256, 0, stream>>>(h, c.elist, c.startA, inc);
        k_mp<unsigned short, unsigned short><<<HALF / 16, 320, 0, stream>>>(h, inc, c.srcH, c.dstH, c.w_t_mp + i * 90000, c.b_t_mp + i * 300);
    }
    k_segsum2<unsigned short, unsigned short><<<SSG, 256, 0, stream>>>(h, c.elist, c.startA, inc);
    k_au<133, float, unsigned short, unsigned short, true><<<NN / 16, 320, 0, stream>>>(c.x, inc, c.w_t_au, c.b_t_au, sh);
    k_lin<300, unsigned short, unsigned short><<<NE / 16, 320, 0, stream>>>(sh, c.ea, c.srcH, c.dstH, c.w_mu_lin, c.b_mu_lin, h);
    for (int i = 0; i < 3; ++i) {
        k_segsum2<unsigned short, unsigned short><<<SSG, 256, 0, stream>>>(h, c.elist, c.startA, inc);
        k_mp<unsigned short, unsigned short><<<HALF / 16, 320, 0, stream>>>(h, inc, c.srcH, c.dstH, c.w_mu_mp + i * 90000, c.b_mu_mp + i * 300);
    }
    k_segsum2<unsigned short, unsigned short><<<SSG, 256, 0, stream>>>(h, c.elist, c.startA, inc);
    k_au<300, unsigned short, unsigned short, float, false><<<NN / 16, 320, 0, stream>>>(sh, inc, c.w_mu_au, c.b_mu_au, rows);
    k_pool<<<NG, 320, 0, stream>>>(rows, c.wat, c.gs, c.mu_g);
    k_lin<300, unsigned short, unsigned short><<<NE / 16, 320, 0, stream>>>(sh, c.ea, c.srcH, c.dstH, c.w_lv_lin, c.b_lv_lin, h);
    for (int i = 0; i < 3; ++i) {
        k_segsum2<unsigned short, unsigned short><<<SSG, 256, 0, stream>>>(h, c.elist, c.startA, inc);
        k_mp<unsigned short, unsigned short><<<HALF / 16, 320, 0, stream>>>(h, inc, c.srcH, c.dstH, c.w_lv_mp + i * 90000, c.b_lv_mp + i * 300);
    }
    k_segsum2<unsigned short, unsigned short><<<SSG, 256, 0, stream>>>(h, c.elist, c.startA, inc);
    k_au<300, unsigned short, unsigned short, float, false><<<NN / 16, 320, 0, stream>>>(sh, inc, c.w_lv_au, c.b_lv_au, rows);
    k_pool<<<NG, 320, 0, stream>>>(rows, c.wat, c.gs, c.lv_g);
}

extern "C" void kernel_launch(void* const* d_in, const int* in_sizes, int n_in,
                              void* d_out, int out_size, void* d_ws, size_t ws_size,
                              hipStream_t stream) {
    float* outp = (float*)d_out;

    // carve totals: MFMA path 199,760,384 B; vector path 198,593,024 B (measured arithmetic)
    const size_t NEED_MFMA = 199800000ull;
    const size_t NEED_VEC  = 199000000ull;
    int tier = (ws_size >= NEED_MFMA) ? 0 : (ws_size >= NEED_VEC) ? 1 : 2;
    if (tier == 2) {
        k_zerof<<<(out_size + 255) / 256, 256, 0, stream>>>(outp, out_size);
        return;
    }

    Ctx c;
    c.x   = (const float*)d_in[0];
    c.ea  = (const float*)d_in[1];
    c.wat = (const float*)d_in[2];
    c.eps = (const float*)d_in[3];
    c.srcH  = (const int*)d_in[4];
    c.dstH  = (const int*)d_in[5];
    c.batch = (const int*)d_in[6];
    const float* w_t_lin_raw  = (const float*)d_in[7];
    c.b_t_lin  = (const float*)d_in[8];
    c.w_t_mp   = (const float*)d_in[9];
    c.b_t_mp   = (const float*)d_in[10];
    const float* w_t_au_raw   = (const float*)d_in[11];
    c.b_t_au   = (const float*)d_in[12];
    const float* w_mu_lin_raw = (const float*)d_in[13];
    c.b_mu_lin = (const float*)d_in[14];
    c.w_mu_mp  = (const float*)d_in[15];
    c.b_mu_mp  = (const float*)d_in[16];
    c.w_mu_au  = (const float*)d_in[17];
    c.b_mu_au  = (const float*)d_in[18];
    const float* w_lv_lin_raw = (const float*)d_in[19];
    c.b_lv_lin = (const float*)d_in[20];
    c.w_lv_mp  = (const float*)d_in[21];
    c.b_lv_mp  = (const float*)d_in[22];
    c.w_lv_au  = (const float*)d_in[23];
    c.b_lv_au  = (const float*)d_in[24];
    c.stream = stream;

    char* p = (char*)d_ws;
    auto alloc = [&](size_t nbytes) { char* q = p; p += (nbytes + 255) & ~(size_t)255; return q; };
    unsigned short* h   = (unsigned short*)alloc((size_t)NE * 300 * 2);   // 96 MB; reused as fp32 rows (exact fit)
    unsigned short* inc = (unsigned short*)alloc((size_t)NN * 300 * 2);   // 48 MB
    unsigned short* sh  = (unsigned short*)alloc((size_t)NN * 300 * 2);   // 48 MB
    float* w_t_lin_p  = (float*)alloc(148 * 300 * 4);
    float* w_t_au_p   = (float*)alloc(436 * 300 * 4);
    float* w_mu_lin_p = (float*)alloc(316 * 300 * 4);
    float* w_lv_lin_p = (float*)alloc(316 * 300 * 4);
    unsigned short *wh = nullptr, *wl = nullptr;
    if (tier == 0) {
        const size_t WSU = (size_t)3 * 190 * 64 * 8;   // ushorts per conv table
        wh = (unsigned short*)alloc(WSU * 2);
        wl = (unsigned short*)alloc(WSU * 2);
    }
    c.mu_g = (float*)alloc((size_t)NG * 300 * 4);
    c.lv_g = (float*)alloc((size_t)NG * 300 * 4);
    int* deg    = (int*)alloc(NN * 4);               // reused as cursor after scan (alias-safe)
    c.startA    = (int*)alloc((NN + 1) * 4);
    c.elist     = (int*)alloc(NE * 4);
    int* degg   = (int*)alloc(NG * 4);
    c.gs        = (int*)alloc((NG + 1) * 4);

    auto wp = [&](const float* in, float* out, int K, int KP) {
        k_wpad<<<(KP * 300 + 255) / 256, 256, 0, stream>>>(in, out, K, KP);
    };
    wp(w_t_lin_raw,  w_t_lin_p,  147, 148);  c.w_t_lin  = w_t_lin_p;
    wp(w_t_au_raw,   w_t_au_p,   433, 436);  c.w_t_au   = w_t_au_p;
    wp(w_mu_lin_raw, w_mu_lin_p, 314, 316);  c.w_mu_lin = w_mu_lin_p;
    wp(w_lv_lin_raw, w_lv_lin_p, 314, 316);  c.w_lv_lin = w_lv_lin_p;

    // CSR (incoming by dst); cursor aliases deg
    k_zeroi<<<(NN + 255) / 256, 256, 0, stream>>>(deg, NN);
    k_hist<<<(NE + 255) / 256, 256, 0, stream>>>(c.srcH, c.dstH, deg);
    k_scan_n<<<1, 1024, 0, stream>>>(deg, c.startA, deg, NN);
    k_fill<<<(NE + 255) / 256, 256, 0, stream>>>(c.srcH, c.dstH, deg, c.elist);

    // graph-CSR over sorted batch
    k_zeroi<<<(NG + 255) / 256, 256, 0, stream>>>(degg, NG);
    k_histg<<<(NN + 255) / 256, 256, 0, stream>>>(c.batch, degg);
    k_scan_n<<<1, 1024, 0, stream>>>(degg, c.gs, (int*)nullptr, NG);

    if (tier == 0)
        run_mfma(c, h, inc, sh, (float*)h, wh, wl);
    else
        run_vec(c, h, inc, sh, (float*)h);

    k_final<<<NG, 320, 0, stream>>>(c.mu_g, c.lv_g, c.eps, outp);
}

// Round 7
// 4765.358 us; speedup vs baseline: 2.2019x; 1.3456x over previous
//
#include <hip/hip_runtime.h>
#include <hip/hip_bf16.h>

#define NN 80000       // nodes
#define NE 160000      // edges (both directions)
#define HALF 80000
#define HID 300
#define NG 1600

typedef __attribute__((ext_vector_type(8))) short bf16x8v;
typedef __attribute__((ext_vector_type(4))) float f32x4v;

// ---------------- helpers ----------------
__device__ __forceinline__ float bf2f_us(unsigned short u) {
    return __uint_as_float(((unsigned int)u) << 16);
}
__device__ __forceinline__ unsigned short f2bf_us(float f) {
    unsigned int u = __float_as_uint(f);
    u += 0x7fff + ((u >> 16) & 1);   // RNE
    return (unsigned short)(u >> 16);
}
__device__ __forceinline__ float ld1(const float* p) { return *p; }
__device__ __forceinline__ float ld1(const unsigned short* p) { return bf2f_us(*p); }
__device__ __forceinline__ void st1(float* p, float v) { *p = v; }
__device__ __forceinline__ void st1(unsigned short* p, float v) { *p = f2bf_us(v); }
__device__ __forceinline__ float4 ld4(const float* p) { return *(const float4*)p; }
__device__ __forceinline__ float4 ld4(const unsigned short* p) {
    ushort4 u = *(const ushort4*)p;
    return make_float4(bf2f_us(u.x), bf2f_us(u.y), bf2f_us(u.z), bf2f_us(u.w));
}
__device__ __forceinline__ void st4(float* p, float4 v) { *(float4*)p = v; }
__device__ __forceinline__ void st4(unsigned short* p, float4 v) {
    ushort4 u; u.x = f2bf_us(v.x); u.y = f2bf_us(v.y); u.z = f2bf_us(v.z); u.w = f2bf_us(v.w);
    *(ushort4*)p = u;
}
__device__ __forceinline__ int clampi(int v, int lo, int hi) {
    return v < lo ? lo : (v > hi ? hi : v);
}

// ---------------- zero-fill ----------------
__global__ void k_zerof(float* __restrict__ p, int n) {
    int i = blockIdx.x * 256 + threadIdx.x; if (i < n) p[i] = 0.f;
}
__global__ void k_zeroi(int* __restrict__ p, int n) {
    int i = blockIdx.x * 256 + threadIdx.x; if (i < n) p[i] = 0;
}

// ---------------- generalized W split+swizzle: K x 300 fp32 -> hi/lo bf16 fragment order ----
// tiles (kt < nkt, ct < 19); lane holds B[k=kt*32+quad*8+j][n=ct*16+(lane&15)], j=0..7
__global__ void k_wsplit_g(const float* __restrict__ W, int Krows, int nkt,
                           unsigned short* __restrict__ whi, unsigned short* __restrict__ wlo) {
    int idx = blockIdx.x * 256 + threadIdx.x;
    if (idx >= nkt * 19 * 64) return;
    int lane = idx & 63;
    int t = idx >> 6;                 // kt*19 + ct
    int kt = t / 19, ct = t - kt * 19;
    int quad = lane >> 4, cr = lane & 15;
    size_t obase = ((size_t)t * 64 + lane) * 8;
    for (int j = 0; j < 8; ++j) {
        int k = kt * 32 + quad * 8 + j;
        int n = ct * 16 + cr;
        float v = (k < Krows && n < 300) ? W[(size_t)k * 300 + n] : 0.f;
        unsigned short hu = f2bf_us(v);
        unsigned short lu = f2bf_us(v - bf2f_us(hu));
        whi[obase + j] = hu;
        wlo[obase + j] = lu;
    }
}

// ---------------- CSR build ----------------
__global__ void k_hist(const int* __restrict__ srcH, const int* __restrict__ dstH, int* __restrict__ deg) {
    int e = blockIdx.x * 256 + threadIdx.x;
    if (e >= NE) return;
    int d = (e < HALF) ? dstH[e] : srcH[e - HALF];
    d = clampi(d, 0, NN - 1);
    atomicAdd(&deg[d], 1);
}
__global__ void k_histg(const int* __restrict__ batch, int* __restrict__ degg) {
    int n = blockIdx.x * 256 + threadIdx.x;
    if (n >= NN) return;
    atomicAdd(&degg[clampi(batch[n], 0, NG - 1)], 1);
}
// alias-safe scan (cursor may alias deg)
__global__ __launch_bounds__(1024) void k_scan_n(const int* __restrict__ deg, int* __restrict__ start,
                                                 int* cursor, int n) {
    __shared__ int part[1024];
    const int t = threadIdx.x;
    const int CH = (n + 1023) / 1024;
    int lo = t * CH;
    int hi = lo + CH; if (hi > n) hi = n;
    int s = 0;
    for (int i = lo; i < hi; ++i) s += deg[i];
    part[t] = s;
    __syncthreads();
    for (int off = 1; off < 1024; off <<= 1) {
        int v = 0;
        if (t >= off) v = part[t - off];
        __syncthreads();
        part[t] += v;
        __syncthreads();
    }
    int run = part[t] - s;
    for (int i = lo; i < hi; ++i) {
        int d = deg[i];
        start[i] = run;
        if (cursor) cursor[i] = run;
        run += d;
    }
    if (t == 1023) start[n] = run;
}
__global__ void k_fill(const int* __restrict__ srcH, const int* __restrict__ dstH,
                       int* __restrict__ cursor, int* __restrict__ elist) {
    int e = blockIdx.x * 256 + threadIdx.x;
    if (e >= NE) return;
    int d = (e < HALF) ? dstH[e] : srcH[e - HALF];
    d = clampi(d, 0, NN - 1);
    int pos = atomicAdd(&cursor[d], 1);
    if (pos >= 0 && pos < NE) elist[pos] = e;
}

// ---------------- segment sum: thread per (node, col-quad), float4 ----------------
template <typename TH, typename TI>
__global__ __launch_bounds__(256) void k_segsum2(const TH* __restrict__ h, const int* __restrict__ elist,
                                                 const int* __restrict__ start, TI* __restrict__ inc) {
    int t = blockIdx.x * 256 + threadIdx.x;
    if (t >= NN * 75) return;
    int n = t / 75, q = t - n * 75;
    int lo = clampi(start[n], 0, NE), hi = clampi(start[n + 1], 0, NE);
    float4 acc = make_float4(0.f, 0.f, 0.f, 0.f);
    for (int j = lo; j < hi; ++j) {
        int e = clampi(elist[j], 0, NE - 1);
        float4 v = ld4(&h[e * 300 + q * 4]);
        acc.x += v.x; acc.y += v.y; acc.z += v.z; acc.w += v.w;
    }
    st4(&inc[n * 300 + q * 4], acc);
}

// ---------------- on-the-fly A split ----------------
__device__ __forceinline__ void split8(const float* ap, bf16x8v& ahi, bf16x8v& alo) {
    float4 v0 = *(const float4*)ap;
    float4 v1 = *(const float4*)(ap + 4);
    float vv[8] = {v0.x, v0.y, v0.z, v0.w, v1.x, v1.y, v1.z, v1.w};
    #pragma unroll
    for (int j = 0; j < 8; ++j) {
        unsigned short hu = f2bf_us(vv[j]);
        ahi[j] = (short)hu;
        alo[j] = (short)f2bf_us(vv[j] - bf2f_us(hu));
    }
}

// ---------------- lin GEMM, MFMA split-bf16 (32 rows/block) ----------------
// h[e] = relu(concat(node_in[src[e]], ea[e]) @ W + b)
template <int NID, typename TN>
__global__ __launch_bounds__(256, 3) void k_lin_mfma(
        const TN* __restrict__ node_in, const float* __restrict__ ea,
        const int* __restrict__ srcH, const int* __restrict__ dstH,
        const unsigned short* __restrict__ whi, const unsigned short* __restrict__ wlo,
        const float* __restrict__ bias, unsigned short* __restrict__ h) {
    constexpr int K = NID + 14;
    constexpr int KP = (K + 31) & ~31;     // 160 or 320
    constexpr int NKT = KP / 32;
    constexpr int LDK = KP + 4;            // ≡4 mod 32 -> 2-way LDS conflicts only
    __shared__ float As[32 * LDK];
    __shared__ int ssrc[32];
    const int tid = threadIdx.x;
    const int lane = tid & 63, wv = tid >> 6;
    const int quad = lane >> 4, cr = lane & 15;
    const int e0 = blockIdx.x * 32;
    if (tid < 32) {
        int e = e0 + tid;
        int s = (e < HALF) ? srcH[e] : dstH[e - HALF];
        ssrc[tid] = clampi(s, 0, NN - 1);
    }
    __syncthreads();
    for (int idx = tid; idx < 32 * KP; idx += 256) {
        int r = idx / KP, k = idx - r * KP;
        float v;
        if (k < NID)    v = ld1(&node_in[(size_t)ssrc[r] * NID + k]);
        else if (k < K) v = ea[(size_t)(e0 + r) * 14 + (k - NID)];
        else            v = 0.f;
        As[r * LDK + k] = v;
    }
    __syncthreads();
    const int rt = wv & 1, c0t = wv >> 1;
    f32x4v acc[10];
    #pragma unroll
    for (int i = 0; i < 10; ++i) {
        int ct = c0t + 2 * i;
        f32x4v a = {0.f, 0.f, 0.f, 0.f};
        if (ct < 19) {
            int col = ct * 16 + cr;
            if (col < 300) { float b = bias[col]; a[0] = b; a[1] = b; a[2] = b; a[3] = b; }
        }
        acc[i] = a;
    }
    for (int kt = 0; kt < NKT; ++kt) {
        bf16x8v ahi, alo;
        split8(&As[(rt * 16 + cr) * LDK + kt * 32 + quad * 8], ahi, alo);
        #pragma unroll
        for (int i = 0; i < 10; ++i) {
            int ct = c0t + 2 * i;
            if (ct >= 19) break;
            size_t base = ((size_t)(kt * 19 + ct) * 64 + lane) * 8;
            bf16x8v bhi = *(const bf16x8v*)&whi[base];
            bf16x8v blo = *(const bf16x8v*)&wlo[base];
            acc[i] = __builtin_amdgcn_mfma_f32_16x16x32_bf16(alo, bhi, acc[i], 0, 0, 0);
            acc[i] = __builtin_amdgcn_mfma_f32_16x16x32_bf16(ahi, blo, acc[i], 0, 0, 0);
            acc[i] = __builtin_amdgcn_mfma_f32_16x16x32_bf16(ahi, bhi, acc[i], 0, 0, 0);
        }
    }
    #pragma unroll
    for (int i = 0; i < 10; ++i) {
        int ct = c0t + 2 * i;
        if (ct >= 19) break;
        int col = ct * 16 + cr;
        if (col >= 300) continue;
        #pragma unroll
        for (int r = 0; r < 4; ++r) {
            int lrow = rt * 16 + quad * 4 + r;
            st1(&h[(size_t)(e0 + lrow) * 300 + col], fmaxf(acc[i][r], 0.f));
        }
    }
}

// ---------------- au GEMM, MFMA split-bf16 (16 rows/block) ----------------
// out[n] = (relu?)(concat(node_in[n], inc[n]) @ W + b)
template <int NID, typename TN, typename TS, bool RELU>
__global__ __launch_bounds__(256, 4) void k_au_mfma(
        const TN* __restrict__ node_in, const unsigned short* __restrict__ inc,
        const unsigned short* __restrict__ whi, const unsigned short* __restrict__ wlo,
        const float* __restrict__ bias, TS* __restrict__ out_rows) {
    constexpr int K = NID + 300;
    constexpr int KP = (K + 31) & ~31;     // 448 or 608
    constexpr int NKT = KP / 32;
    constexpr int LDK = KP + 4;
    __shared__ float As[16 * LDK];
    const int tid = threadIdx.x;
    const int lane = tid & 63, wv = tid >> 6;
    const int quad = lane >> 4, cr = lane & 15;
    const int n0 = blockIdx.x * 16;
    for (int idx = tid; idx < 16 * KP; idx += 256) {
        int r = idx / KP, k = idx - r * KP;
        int n = n0 + r;
        float v;
        if (k < NID)    v = ld1(&node_in[(size_t)n * NID + k]);
        else if (k < K) v = ld1(&inc[(size_t)n * 300 + (k - NID)]);
        else            v = 0.f;
        As[r * LDK + k] = v;
    }
    __syncthreads();
    f32x4v acc[5];
    #pragma unroll
    for (int i = 0; i < 5; ++i) {
        int ct = wv + 4 * i;
        f32x4v a = {0.f, 0.f, 0.f, 0.f};
        if (ct < 19) {
            int col = ct * 16 + cr;
            if (col < 300) { float b = bias[col]; a[0] = b; a[1] = b; a[2] = b; a[3] = b; }
        }
        acc[i] = a;
    }
    for (int kt = 0; kt < NKT; ++kt) {
        bf16x8v ahi, alo;
        split8(&As[cr * LDK + kt * 32 + quad * 8], ahi, alo);
        #pragma unroll
        for (int i = 0; i < 5; ++i) {
            int ct = wv + 4 * i;
            if (ct >= 19) break;
            size_t base = ((size_t)(kt * 19 + ct) * 64 + lane) * 8;
            bf16x8v bhi = *(const bf16x8v*)&whi[base];
            bf16x8v blo = *(const bf16x8v*)&wlo[base];
            acc[i] = __builtin_amdgcn_mfma_f32_16x16x32_bf16(alo, bhi, acc[i], 0, 0, 0);
            acc[i] = __builtin_amdgcn_mfma_f32_16x16x32_bf16(ahi, blo, acc[i], 0, 0, 0);
            acc[i] = __builtin_amdgcn_mfma_f32_16x16x32_bf16(ahi, bhi, acc[i], 0, 0, 0);
        }
    }
    #pragma unroll
    for (int i = 0; i < 5; ++i) {
        int ct = wv + 4 * i;
        if (ct >= 19) break;
        int col = ct * 16 + cr;
        if (col >= 300) continue;
        #pragma unroll
        for (int r = 0; r < 4; ++r) {
            int n = n0 + quad * 4 + r;
            float v = acc[i][r];
            st1(&out_rows[(size_t)n * 300 + col], RELU ? fmaxf(v, 0.f) : v);
        }
    }
}

// ---------------- mp GEMM, MFMA split-bf16 (proven round 6) ----------------
// h[e] = relu(h[e] + (inc[src[e]] - h[rev(e)]) @ W + b), 32 rows = 16 pairs / block
#define LDA 324
template <typename TH, typename TI>
__global__ __launch_bounds__(256, 3) void k_mp_mfma(
        TH* __restrict__ h, const TI* __restrict__ inc,
        const int* __restrict__ srcH, const int* __restrict__ dstH,
        const unsigned short* __restrict__ whi, const unsigned short* __restrict__ wlo,
        const float* __restrict__ bias) {
    __shared__ float Hs[32 * LDA];
    __shared__ int ssrc[32];
    const int tid = threadIdx.x;
    const int lane = tid & 63;
    const int wv = tid >> 6;
    const int quad = lane >> 4, cr = lane & 15;
    const int p0 = blockIdx.x * 16;
    if (tid < 32) {
        int r = tid;
        int e = (r < 16) ? (p0 + r) : (p0 + r - 16 + HALF);
        int s = (e < HALF) ? srcH[e] : dstH[e - HALF];
        ssrc[r] = clampi(s, 0, NN - 1);
    }
    for (int idx = tid; idx < 32 * 80; idx += 256) {
        int r = idx / 80, q4 = idx - r * 80;
        int col = q4 * 4;
        float4 v = make_float4(0.f, 0.f, 0.f, 0.f);
        if (col < 300) {
            int e = (r < 16) ? (p0 + r) : (p0 + r - 16 + HALF);
            v = ld4(&h[(size_t)e * 300 + col]);
        }
        *(float4*)&Hs[r * LDA + col] = v;
    }
    __syncthreads();
    const int rt = wv & 1;
    const int c0t = wv >> 1;
    f32x4v acc[10];
    #pragma unroll
    for (int i = 0; i < 10; ++i) {
        int ct = c0t + 2 * i;
        f32x4v a = {0.f, 0.f, 0.f, 0.f};
        if (ct < 19) {
            int col = ct * 16 + cr;
            if (col < 300) {
                float b = bias[col];
                #pragma unroll
                for (int r = 0; r < 4; ++r)
                    a[r] = Hs[(rt * 16 + quad * 4 + r) * LDA + col] + b;
            }
        }
        acc[i] = a;
    }
    __syncthreads();
    for (int idx = tid; idx < 16 * 80; idx += 256) {
        int r = idx / 80, q4 = idx - r * 80;
        int col = q4 * 4;
        float4 a = *(const float4*)&Hs[r * LDA + col];
        float4 b = *(const float4*)&Hs[(r + 16) * LDA + col];
        float4 i1 = make_float4(0.f, 0.f, 0.f, 0.f), i2 = i1;
        if (col < 300) {
            i1 = ld4(&inc[(size_t)ssrc[r] * 300 + col]);
            i2 = ld4(&inc[(size_t)ssrc[r + 16] * 300 + col]);
        }
        *(float4*)&Hs[r * LDA + col]        = make_float4(i1.x - b.x, i1.y - b.y, i1.z - b.z, i1.w - b.w);
        *(float4*)&Hs[(r + 16) * LDA + col] = make_float4(i2.x - a.x, i2.y - a.y, i2.z - a.z, i2.w - a.w);
    }
    __syncthreads();
    for (int kt = 0; kt < 10; ++kt) {
        bf16x8v ahi, alo;
        split8(&Hs[(rt * 16 + cr) * LDA + kt * 32 + quad * 8], ahi, alo);
        #pragma unroll
        for (int i = 0; i < 10; ++i) {
            int ct = c0t + 2 * i;
            if (ct >= 19) break;
            size_t base = ((size_t)(kt * 19 + ct) * 64 + lane) * 8;
            bf16x8v bhi = *(const bf16x8v*)&whi[base];
            bf16x8v blo = *(const bf16x8v*)&wlo[base];
            acc[i] = __builtin_amdgcn_mfma_f32_16x16x32_bf16(alo, bhi, acc[i], 0, 0, 0);
            acc[i] = __builtin_amdgcn_mfma_f32_16x16x32_bf16(ahi, blo, acc[i], 0, 0, 0);
            acc[i] = __builtin_amdgcn_mfma_f32_16x16x32_bf16(ahi, bhi, acc[i], 0, 0, 0);
        }
    }
    #pragma unroll
    for (int i = 0; i < 10; ++i) {
        int ct = c0t + 2 * i;
        if (ct >= 19) break;
        int col = ct * 16 + cr;
        if (col >= 300) continue;
        #pragma unroll
        for (int r = 0; r < 4; ++r) {
            int lrow = rt * 16 + quad * 4 + r;
            int e = (lrow < 16) ? (p0 + lrow) : (p0 + lrow - 16 + HALF);
            st1(&h[(size_t)e * 300 + col], fmaxf(acc[i][r], 0.f));
        }
    }
}

// ---------------- pooling + reparam ----------------
__global__ __launch_bounds__(320) void k_pool(const float* __restrict__ rows, const float* __restrict__ wat,
                                              const int* __restrict__ gs, float* __restrict__ outg) {
    int g = blockIdx.x, c = threadIdx.x;
    if (c >= 300) return;
    int lo = clampi(gs[g], 0, NN), hi = clampi(gs[g + 1], 0, NN);
    float acc = 0.f;
    for (int n = lo; n < hi; ++n)
        acc += rows[n * 300 + c] * wat[n];
    float cn = fmaxf((float)(hi - lo), 1.f);
    outg[g * 300 + c] = acc / cn;
}
__global__ __launch_bounds__(320) void k_final(const float* __restrict__ mu_g, const float* __restrict__ lv_g,
                                               const float* __restrict__ eps, float* __restrict__ out) {
    int g = blockIdx.x, c = threadIdx.x;
    if (c >= 300) return;
    out[g * 300 + c] = mu_g[g * 300 + c] + expf(0.5f * lv_g[g * 300 + c]) * eps[g * 300 + c];
}

extern "C" void kernel_launch(void* const* d_in, const int* in_sizes, int n_in,
                              void* d_out, int out_size, void* d_ws, size_t ws_size,
                              hipStream_t stream) {
    float* outp = (float*)d_out;

    const size_t NEED = 199500000ull;   // exact carve = 199,429,120 B; ws proven >= 200,000,000
    if (ws_size < NEED) {
        k_zerof<<<(out_size + 255) / 256, 256, 0, stream>>>(outp, out_size);
        return;
    }

    const float* x   = (const float*)d_in[0];
    const float* ea  = (const float*)d_in[1];
    const float* wat = (const float*)d_in[2];
    const float* eps = (const float*)d_in[3];
    const int* srcH  = (const int*)d_in[4];
    const int* dstH  = (const int*)d_in[5];
    const int* batch = (const int*)d_in[6];
    const float* w_t_lin  = (const float*)d_in[7];
    const float* b_t_lin  = (const float*)d_in[8];
    const float* w_t_mp   = (const float*)d_in[9];
    const float* b_t_mp   = (const float*)d_in[10];
    const float* w_t_au   = (const float*)d_in[11];
    const float* b_t_au   = (const float*)d_in[12];
    const float* w_mu_lin = (const float*)d_in[13];
    const float* b_mu_lin = (const float*)d_in[14];
    const float* w_mu_mp  = (const float*)d_in[15];
    const float* b_mu_mp  = (const float*)d_in[16];
    const float* w_mu_au  = (const float*)d_in[17];
    const float* b_mu_au  = (const float*)d_in[18];
    const float* w_lv_lin = (const float*)d_in[19];
    const float* b_lv_lin = (const float*)d_in[20];
    const float* w_lv_mp  = (const float*)d_in[21];
    const float* b_lv_mp  = (const float*)d_in[22];
    const float* w_lv_au  = (const float*)d_in[23];
    const float* b_lv_au  = (const float*)d_in[24];

    char* p = (char*)d_ws;
    auto alloc = [&](size_t nbytes) { char* q = p; p += (nbytes + 255) & ~(size_t)255; return q; };
    unsigned short* h   = (unsigned short*)alloc((size_t)NE * 300 * 2);   // 96 MB; reused as fp32 rows
    unsigned short* inc = (unsigned short*)alloc((size_t)NN * 300 * 2);   // 48 MB
    unsigned short* sh  = (unsigned short*)alloc((size_t)NN * 300 * 2);   // 48 MB
    // mp tables (3 layers x 10kt x 19ct), re-split per conv
    const size_t MPU = (size_t)3 * 10 * 19 * 512;   // ushorts
    unsigned short* wh_mp = (unsigned short*)alloc(MPU * 2);
    unsigned short* wl_mp = (unsigned short*)alloc(MPU * 2);
    // lin+au tables, re-split per conv: max (10+19) kt-tiles x 19 ct
    const size_t LAU = (size_t)29 * 19 * 512;       // ushorts
    unsigned short* wh_la = (unsigned short*)alloc(LAU * 2);
    unsigned short* wl_la = (unsigned short*)alloc(LAU * 2);
    float* mu_g = (float*)alloc((size_t)NG * 300 * 4);
    float* lv_g = (float*)alloc((size_t)NG * 300 * 4);
    int* deg    = (int*)alloc(NN * 4);               // reused as cursor (alias-safe)
    int* startA = (int*)alloc((NN + 1) * 4);
    int* elist  = (int*)alloc(NE * 4);
    int* degg   = (int*)alloc(NG * 4);
    int* gs     = (int*)alloc((NG + 1) * 4);

    // ---- CSR (incoming by dst) ----
    k_zeroi<<<(NN + 255) / 256, 256, 0, stream>>>(deg, NN);
    k_hist<<<(NE + 255) / 256, 256, 0, stream>>>(srcH, dstH, deg);
    k_scan_n<<<1, 1024, 0, stream>>>(deg, startA, deg, NN);
    k_fill<<<(NE + 255) / 256, 256, 0, stream>>>(srcH, dstH, deg, elist);
    // ---- graph-CSR over sorted batch ----
    k_zeroi<<<(NG + 255) / 256, 256, 0, stream>>>(degg, NG);
    k_histg<<<(NN + 255) / 256, 256, 0, stream>>>(batch, degg);
    k_scan_n<<<1, 1024, 0, stream>>>(degg, gs, (int*)nullptr, NG);

    const int SSG = (NN * 75 + 255) / 256;
    const size_t MP_L = (size_t)10 * 19 * 512;      // ushorts per mp layer
    float* rows = (float*)h;                         // fp32 rows alias (h dead at that point)
    auto wsplit = [&](const float* W, int K, int nkt, unsigned short* whi, unsigned short* wlo) {
        k_wsplit_g<<<(nkt * 19 * 64 + 255) / 256, 256, 0, stream>>>(W, K, nkt, whi, wlo);
    };

    // ================= conv t =================
    for (int i = 0; i < 3; ++i)
        wsplit(w_t_mp + i * 90000, 300, 10, wh_mp + i * MP_L, wl_mp + i * MP_L);
    wsplit(w_t_lin, 147, 5, wh_la, wl_la);                         // lin at offset 0
    const size_t AU_T = (size_t)5 * 19 * 512;
    wsplit(w_t_au, 433, 14, wh_la + AU_T, wl_la + AU_T);           // au after 5 kt-tiles
    k_lin_mfma<133, float><<<NE / 32, 256, 0, stream>>>(x, ea, srcH, dstH, wh_la, wl_la, b_t_lin, h);
    for (int i = 0; i < 3; ++i) {
        k_segsum2<unsigned short, unsigned short><<<SSG, 256, 0, stream>>>(h, elist, startA, inc);
        k_mp_mfma<unsigned short, unsigned short><<<HALF / 16, 256, 0, stream>>>(
            h, inc, srcH, dstH, wh_mp + i * MP_L, wl_mp + i * MP_L, b_t_mp + i * 300);
    }
    k_segsum2<unsigned short, unsigned short><<<SSG, 256, 0, stream>>>(h, elist, startA, inc);
    k_au_mfma<133, float, unsigned short, true><<<NN / 16, 256, 0, stream>>>(x, inc, wh_la + AU_T, wl_la + AU_T, b_t_au, sh);

    // ================= conv mu =================
    for (int i = 0; i < 3; ++i)
        wsplit(w_mu_mp + i * 90000, 300, 10, wh_mp + i * MP_L, wl_mp + i * MP_L);
    wsplit(w_mu_lin, 314, 10, wh_la, wl_la);
    const size_t AU_MU = (size_t)10 * 19 * 512;
    wsplit(w_mu_au, 600, 19, wh_la + AU_MU, wl_la + AU_MU);
    k_lin_mfma<300, unsigned short><<<NE / 32, 256, 0, stream>>>(sh, ea, srcH, dstH, wh_la, wl_la, b_mu_lin, h);
    for (int i = 0; i < 3; ++i) {
        k_segsum2<unsigned short, unsigned short><<<SSG, 256, 0, stream>>>(h, elist, startA, inc);
        k_mp_mfma<unsigned short, unsigned short><<<HALF / 16, 256, 0, stream>>>(
            h, inc, srcH, dstH, wh_mp + i * MP_L, wl_mp + i * MP_L, b_mu_mp + i * 300);
    }
    k_segsum2<unsigned short, unsigned short><<<SSG, 256, 0, stream>>>(h, elist, startA, inc);
    k_au_mfma<300, unsigned short, float, false><<<NN / 16, 256, 0, stream>>>(sh, inc, wh_la + AU_MU, wl_la + AU_MU, b_mu_au, rows);
    k_pool<<<NG, 320, 0, stream>>>(rows, wat, gs, mu_g);

    // ================= conv lv =================
    for (int i = 0; i < 3; ++i)
        wsplit(w_lv_mp + i * 90000, 300, 10, wh_mp + i * MP_L, wl_mp + i * MP_L);
    wsplit(w_lv_lin, 314, 10, wh_la, wl_la);
    wsplit(w_lv_au, 600, 19, wh_la + AU_MU, wl_la + AU_MU);
    k_lin_mfma<300, unsigned short><<<NE / 32, 256, 0, stream>>>(sh, ea, srcH, dstH, wh_la, wl_la, b_lv_lin, h);
    for (int i = 0; i < 3; ++i) {
        k_segsum2<unsigned short, unsigned short><<<SSG, 256, 0, stream>>>(h, elist, startA, inc);
        k_mp_mfma<unsigned short, unsigned short><<<HALF / 16, 256, 0, stream>>>(
            h, inc, srcH, dstH, wh_mp + i * MP_L, wl_mp + i * MP_L, b_lv_mp + i * 300);
    }
    k_segsum2<unsigned short, unsigned short><<<SSG, 256, 0, stream>>>(h, elist, startA, inc);
    k_au_mfma<300, unsigned short, float, false><<<NN / 16, 256, 0, stream>>>(sh, inc, wh_la + AU_MU, wl_la + AU_MU, b_lv_au, rows);
    k_pool<<<NG, 320, 0, stream>>>(rows, wat, gs, lv_g);

    // ---- reparam ----
    k_final<<<NG, 320, 0, stream>>>(mu_g, lv_g, eps, outp);
}

// Round 8
// 4233.472 us; speedup vs baseline: 2.4786x; 1.1256x over previous
//
#include <hip/hip_runtime.h>
#include <hip/hip_bf16.h>

#define NN 80000       // nodes
#define NE 160000      // edges (both directions)
#define HALF 80000
#define HID 300
#define NG 1600

typedef __attribute__((ext_vector_type(8))) short bf16x8v;
typedef __attribute__((ext_vector_type(4))) float f32x4v;

// ---------------- helpers ----------------
__device__ __forceinline__ float bf2f_us(unsigned short u) {
    return __uint_as_float(((unsigned int)u) << 16);
}
__device__ __forceinline__ unsigned short f2bf_us(float f) {
    unsigned int u = __float_as_uint(f);
    u += 0x7fff + ((u >> 16) & 1);   // RNE
    return (unsigned short)(u >> 16);
}
__device__ __forceinline__ float ld1(const float* p) { return *p; }
__device__ __forceinline__ float ld1(const unsigned short* p) { return bf2f_us(*p); }
__device__ __forceinline__ void st1(float* p, float v) { *p = v; }
__device__ __forceinline__ void st1(unsigned short* p, float v) { *p = f2bf_us(v); }
__device__ __forceinline__ float4 ld4(const float* p) { return *(const float4*)p; }
__device__ __forceinline__ float4 ld4(const unsigned short* p) {
    ushort4 u = *(const ushort4*)p;
    return make_float4(bf2f_us(u.x), bf2f_us(u.y), bf2f_us(u.z), bf2f_us(u.w));
}
__device__ __forceinline__ void st4(float* p, float4 v) { *(float4*)p = v; }
__device__ __forceinline__ void st4(unsigned short* p, float4 v) {
    ushort4 u; u.x = f2bf_us(v.x); u.y = f2bf_us(v.y); u.z = f2bf_us(v.z); u.w = f2bf_us(v.w);
    *(ushort4*)p = u;
}
__device__ __forceinline__ int clampi(int v, int lo, int hi) {
    return v < lo ? lo : (v > hi ? hi : v);
}

// ---------------- zero-fill ----------------
__global__ void k_zerof(float* __restrict__ p, int n) {
    int i = blockIdx.x * 256 + threadIdx.x; if (i < n) p[i] = 0.f;
}
__global__ void k_zeroi(int* __restrict__ p, int n) {
    int i = blockIdx.x * 256 + threadIdx.x; if (i < n) p[i] = 0;
}

// ---------------- W split+swizzle: K x 300 fp32 -> hi/lo bf16 fragment order ----------------
// tiles (kt < nkt, ct < 19); lane holds B[k=kt*32+quad*8+j][n=ct*16+(lane&15)], j=0..7
__global__ void k_wsplit_g(const float* __restrict__ W, int Krows, int nkt,
                           unsigned short* __restrict__ whi, unsigned short* __restrict__ wlo) {
    int idx = blockIdx.x * 256 + threadIdx.x;
    if (idx >= nkt * 19 * 64) return;
    int lane = idx & 63;
    int t = idx >> 6;                 // kt*19 + ct
    int kt = t / 19, ct = t - kt * 19;
    int quad = lane >> 4, cr = lane & 15;
    size_t obase = ((size_t)t * 64 + lane) * 8;
    for (int j = 0; j < 8; ++j) {
        int k = kt * 32 + quad * 8 + j;
        int n = ct * 16 + cr;
        float v = (k < Krows && n < 300) ? W[(size_t)k * 300 + n] : 0.f;
        unsigned short hu = f2bf_us(v);
        unsigned short lu = f2bf_us(v - bf2f_us(hu));
        whi[obase + j] = hu;
        wlo[obase + j] = lu;
    }
}

// ---------------- CSR build ----------------
__global__ void k_hist(const int* __restrict__ srcH, const int* __restrict__ dstH, int* __restrict__ deg) {
    int e = blockIdx.x * 256 + threadIdx.x;
    if (e >= NE) return;
    int d = (e < HALF) ? dstH[e] : srcH[e - HALF];
    d = clampi(d, 0, NN - 1);
    atomicAdd(&deg[d], 1);
}
__global__ void k_histg(const int* __restrict__ batch, int* __restrict__ degg) {
    int n = blockIdx.x * 256 + threadIdx.x;
    if (n >= NN) return;
    atomicAdd(&degg[clampi(batch[n], 0, NG - 1)], 1);
}
// alias-safe scan (cursor may alias deg)
__global__ __launch_bounds__(1024) void k_scan_n(const int* __restrict__ deg, int* __restrict__ start,
                                                 int* cursor, int n) {
    __shared__ int part[1024];
    const int t = threadIdx.x;
    const int CH = (n + 1023) / 1024;
    int lo = t * CH;
    int hi = lo + CH; if (hi > n) hi = n;
    int s = 0;
    for (int i = lo; i < hi; ++i) s += deg[i];
    part[t] = s;
    __syncthreads();
    for (int off = 1; off < 1024; off <<= 1) {
        int v = 0;
        if (t >= off) v = part[t - off];
        __syncthreads();
        part[t] += v;
        __syncthreads();
    }
    int run = part[t] - s;
    for (int i = lo; i < hi; ++i) {
        int d = deg[i];
        start[i] = run;
        if (cursor) cursor[i] = run;
        run += d;
    }
    if (t == 1023) start[n] = run;
}
__global__ void k_fill(const int* __restrict__ srcH, const int* __restrict__ dstH,
                       int* __restrict__ cursor, int* __restrict__ elist) {
    int e = blockIdx.x * 256 + threadIdx.x;
    if (e >= NE) return;
    int d = (e < HALF) ? dstH[e] : srcH[e - HALF];
    d = clampi(d, 0, NN - 1);
    int pos = atomicAdd(&cursor[d], 1);
    if (pos >= 0 && pos < NE) elist[pos] = e;
}

// ---------------- segment sum: thread per (node, col-quad), bf16 in/out ----------------
__global__ __launch_bounds__(256) void k_segsum2(const unsigned short* __restrict__ h,
                                                 const int* __restrict__ elist,
                                                 const int* __restrict__ start,
                                                 unsigned short* __restrict__ inc) {
    int t = blockIdx.x * 256 + threadIdx.x;
    if (t >= NN * 75) return;
    int n = t / 75, q = t - n * 75;
    int lo = clampi(start[n], 0, NE), hi = clampi(start[n + 1], 0, NE);
    float4 acc = make_float4(0.f, 0.f, 0.f, 0.f);
    for (int j = lo; j < hi; ++j) {
        int e = clampi(elist[j], 0, NE - 1);
        float4 v = ld4(&h[(size_t)e * 300 + q * 4]);
        acc.x += v.x; acc.y += v.y; acc.z += v.z; acc.w += v.w;
    }
    st4(&inc[(size_t)n * 300 + q * 4], acc);
}

// ---------------- lin GEMM, MFMA (bf16 A-tile, 2 MFMA/tile), 32 rows/block ----------------
// h[e] = relu(concat(node_in[src[e]], ea[e]) @ W + b)
template <int NID, typename TN>
__global__ __launch_bounds__(256, 6) void k_lin_mfma(
        const TN* __restrict__ node_in, const float* __restrict__ ea,
        const int* __restrict__ srcH, const int* __restrict__ dstH,
        const unsigned short* __restrict__ whi, const unsigned short* __restrict__ wlo,
        const float* __restrict__ bias, unsigned short* __restrict__ h) {
    constexpr int K = NID + 14;
    constexpr int KP = (K + 31) & ~31;     // 160 or 320
    constexpr int NKT = KP / 32;
    constexpr int LDK = KP + 8;            // mult of 8 -> 16B-aligned rows; 2-way LDS conflicts only
    __shared__ unsigned short As[32 * LDK];
    __shared__ int ssrc[32];
    const int tid = threadIdx.x;
    const int lane = tid & 63, wv = tid >> 6;
    const int quad = lane >> 4, cr = lane & 15;
    const int e0 = blockIdx.x * 32;
    if (tid < 32) {
        int e = e0 + tid;
        int s = (e < HALF) ? srcH[e] : dstH[e - HALF];
        ssrc[tid] = clampi(s, 0, NN - 1);
    }
    __syncthreads();
    for (int idx = tid; idx < 32 * KP; idx += 256) {
        int r = idx / KP, k = idx - r * KP;
        float v;
        if (k < NID)    v = ld1(&node_in[(size_t)ssrc[r] * NID + k]);
        else if (k < K) v = ea[(size_t)(e0 + r) * 14 + (k - NID)];
        else            v = 0.f;
        As[r * LDK + k] = f2bf_us(v);
    }
    __syncthreads();
    const int rt = wv & 1, c0t = wv >> 1;
    f32x4v acc[10];
    #pragma unroll
    for (int i = 0; i < 10; ++i) {
        int ct = c0t + 2 * i;
        f32x4v a = {0.f, 0.f, 0.f, 0.f};
        if (ct < 19) {
            int col = ct * 16 + cr;
            if (col < 300) { float b = bias[col]; a[0] = b; a[1] = b; a[2] = b; a[3] = b; }
        }
        acc[i] = a;
    }
    for (int kt = 0; kt < NKT; ++kt) {
        bf16x8v a = *(const bf16x8v*)&As[(rt * 16 + cr) * LDK + kt * 32 + quad * 8];
        #pragma unroll
        for (int i = 0; i < 10; ++i) {
            int ct = c0t + 2 * i;
            if (ct >= 19) break;
            size_t base = ((size_t)(kt * 19 + ct) * 64 + lane) * 8;
            bf16x8v bhi = *(const bf16x8v*)&whi[base];
            bf16x8v blo = *(const bf16x8v*)&wlo[base];
            acc[i] = __builtin_amdgcn_mfma_f32_16x16x32_bf16(a, blo, acc[i], 0, 0, 0);
            acc[i] = __builtin_amdgcn_mfma_f32_16x16x32_bf16(a, bhi, acc[i], 0, 0, 0);
        }
    }
    #pragma unroll
    for (int i = 0; i < 10; ++i) {
        int ct = c0t + 2 * i;
        if (ct >= 19) break;
        int col = ct * 16 + cr;
        if (col >= 300) continue;
        #pragma unroll
        for (int r = 0; r < 4; ++r) {
            int lrow = rt * 16 + quad * 4 + r;
            st1(&h[(size_t)(e0 + lrow) * 300 + col], fmaxf(acc[i][r], 0.f));
        }
    }
}

// ---------------- au GEMM, MFMA (bf16 A-tile, 2 MFMA/tile), 16 rows/block ----------------
// out[n] = (relu?)(concat(node_in[n], inc[n]) @ W + b) ; output bf16
template <int NID, typename TN, bool RELU>
__global__ __launch_bounds__(256, 6) void k_au_mfma(
        const TN* __restrict__ node_in, const unsigned short* __restrict__ inc,
        const unsigned short* __restrict__ whi, const unsigned short* __restrict__ wlo,
        const float* __restrict__ bias, unsigned short* __restrict__ out_rows) {
    constexpr int K = NID + 300;
    constexpr int KP = (K + 31) & ~31;     // 448 or 608
    constexpr int NKT = KP / 32;
    constexpr int LDK = KP + 8;
    __shared__ unsigned short As[16 * LDK];
    const int tid = threadIdx.x;
    const int lane = tid & 63, wv = tid >> 6;
    const int quad = lane >> 4, cr = lane & 15;
    const int n0 = blockIdx.x * 16;
    for (int idx = tid; idx < 16 * KP; idx += 256) {
        int r = idx / KP, k = idx - r * KP;
        int n = n0 + r;
        float v;
        if (k < NID)    v = ld1(&node_in[(size_t)n * NID + k]);
        else if (k < K) v = ld1(&inc[(size_t)n * 300 + (k - NID)]);
        else            v = 0.f;
        As[r * LDK + k] = f2bf_us(v);
    }
    __syncthreads();
    f32x4v acc[5];
    #pragma unroll
    for (int i = 0; i < 5; ++i) {
        int ct = wv + 4 * i;
        f32x4v a = {0.f, 0.f, 0.f, 0.f};
        if (ct < 19) {
            int col = ct * 16 + cr;
            if (col < 300) { float b = bias[col]; a[0] = b; a[1] = b; a[2] = b; a[3] = b; }
        }
        acc[i] = a;
    }
    for (int kt = 0; kt < NKT; ++kt) {
        bf16x8v a = *(const bf16x8v*)&As[cr * LDK + kt * 32 + quad * 8];
        #pragma unroll
        for (int i = 0; i < 5; ++i) {
            int ct = wv + 4 * i;
            if (ct >= 19) break;
            size_t base = ((size_t)(kt * 19 + ct) * 64 + lane) * 8;
            bf16x8v bhi = *(const bf16x8v*)&whi[base];
            bf16x8v blo = *(const bf16x8v*)&wlo[base];
            acc[i] = __builtin_amdgcn_mfma_f32_16x16x32_bf16(a, blo, acc[i], 0, 0, 0);
            acc[i] = __builtin_amdgcn_mfma_f32_16x16x32_bf16(a, bhi, acc[i], 0, 0, 0);
        }
    }
    #pragma unroll
    for (int i = 0; i < 5; ++i) {
        int ct = wv + 4 * i;
        if (ct >= 19) break;
        int col = ct * 16 + cr;
        if (col >= 300) continue;
        #pragma unroll
        for (int r = 0; r < 4; ++r) {
            int n = n0 + quad * 4 + r;
            float v = acc[i][r];
            st1(&out_rows[(size_t)n * 300 + col], RELU ? fmaxf(v, 0.f) : v);
        }
    }
}

// ---------------- mp GEMM, MFMA (bf16 A-tile, 2 MFMA/tile) ----------------
// h[e] = relu(h[e] + (inc[src[e]] - h[rev(e)]) @ W + b), 32 rows = 16 pairs / block
__global__ __launch_bounds__(256, 6) void k_mp_mfma(
        unsigned short* __restrict__ h, const unsigned short* __restrict__ inc,
        const int* __restrict__ srcH, const int* __restrict__ dstH,
        const unsigned short* __restrict__ whi, const unsigned short* __restrict__ wlo,
        const float* __restrict__ bias) {
    constexpr int LDK = 328;               // mult of 8; 2-way conflicts only
    __shared__ unsigned short Hs[32 * LDK];
    __shared__ int ssrc[32];
    const int tid = threadIdx.x;
    const int lane = tid & 63;
    const int wv = tid >> 6;
    const int quad = lane >> 4, cr = lane & 15;
    const int p0 = blockIdx.x * 16;
    if (tid < 32) {
        int r = tid;
        int e = (r < 16) ? (p0 + r) : (p0 + r - 16 + HALF);
        int s = (e < HALF) ? srcH[e] : dstH[e - HALF];
        ssrc[r] = clampi(s, 0, NN - 1);
    }
    // stage h_old rows (bf16 direct copy; zero pad cols [300,328))
    for (int idx = tid; idx < 32 * 82; idx += 256) {
        int r = idx / 82, q = idx - r * 82;
        int col = q * 4;
        ushort4 v = make_ushort4(0, 0, 0, 0);
        if (col < 300) {
            int e = (r < 16) ? (p0 + r) : (p0 + r - 16 + HALF);
            v = *(const ushort4*)&h[(size_t)e * 300 + col];
        }
        *(ushort4*)&Hs[r * LDK + col] = v;
    }
    __syncthreads();
    // C init: acc = h_old + bias
    const int rt = wv & 1;
    const int c0t = wv >> 1;
    f32x4v acc[10];
    #pragma unroll
    for (int i = 0; i < 10; ++i) {
        int ct = c0t + 2 * i;
        f32x4v a = {0.f, 0.f, 0.f, 0.f};
        if (ct < 19) {
            int col = ct * 16 + cr;
            if (col < 300) {
                float b = bias[col];
                #pragma unroll
                for (int r = 0; r < 4; ++r)
                    a[r] = bf2f_us(Hs[(rt * 16 + quad * 4 + r) * LDK + col]) + b;
            }
        }
        acc[i] = a;
    }
    __syncthreads();
    // pairwise in-place transform: Hs[r] <- bf16(inc[ssrc[r]] - Hs[r^16])
    for (int idx = tid; idx < 16 * 75; idx += 256) {
        int r = idx / 75, q = idx - r * 75;
        int col = q * 4;
        float4 a = ld4(&Hs[r * LDK + col]);
        float4 b = ld4(&Hs[(r + 16) * LDK + col]);
        float4 i1 = ld4(&inc[(size_t)ssrc[r] * 300 + col]);
        float4 i2 = ld4(&inc[(size_t)ssrc[r + 16] * 300 + col]);
        st4(&Hs[r * LDK + col],        make_float4(i1.x - b.x, i1.y - b.y, i1.z - b.z, i1.w - b.w));
        st4(&Hs[(r + 16) * LDK + col], make_float4(i2.x - a.x, i2.y - a.y, i2.z - a.z, i2.w - a.w));
    }
    __syncthreads();
    for (int kt = 0; kt < 10; ++kt) {
        bf16x8v a = *(const bf16x8v*)&Hs[(rt * 16 + cr) * LDK + kt * 32 + quad * 8];
        #pragma unroll
        for (int i = 0; i < 10; ++i) {
            int ct = c0t + 2 * i;
            if (ct >= 19) break;
            size_t base = ((size_t)(kt * 19 + ct) * 64 + lane) * 8;
            bf16x8v bhi = *(const bf16x8v*)&whi[base];
            bf16x8v blo = *(const bf16x8v*)&wlo[base];
            acc[i] = __builtin_amdgcn_mfma_f32_16x16x32_bf16(a, blo, acc[i], 0, 0, 0);
            acc[i] = __builtin_amdgcn_mfma_f32_16x16x32_bf16(a, bhi, acc[i], 0, 0, 0);
        }
    }
    #pragma unroll
    for (int i = 0; i < 10; ++i) {
        int ct = c0t + 2 * i;
        if (ct >= 19) break;
        int col = ct * 16 + cr;
        if (col >= 300) continue;
        #pragma unroll
        for (int r = 0; r < 4; ++r) {
            int lrow = rt * 16 + quad * 4 + r;
            int e = (lrow < 16) ? (p0 + lrow) : (p0 + lrow - 16 + HALF);
            st1(&h[(size_t)e * 300 + col], fmaxf(acc[i][r], 0.f));
        }
    }
}

// ---------------- pooling (bf16 rows) + reparam ----------------
__global__ __launch_bounds__(320) void k_pool(const unsigned short* __restrict__ rows,
                                              const float* __restrict__ wat,
                                              const int* __restrict__ gs, float* __restrict__ outg) {
    int g = blockIdx.x, c = threadIdx.x;
    if (c >= 300) return;
    int lo = clampi(gs[g], 0, NN), hi = clampi(gs[g + 1], 0, NN);
    float acc = 0.f;
    for (int n = lo; n < hi; ++n)
        acc += bf2f_us(rows[(size_t)n * 300 + c]) * wat[n];
    float cn = fmaxf((float)(hi - lo), 1.f);
    outg[g * 300 + c] = acc / cn;
}
__global__ __launch_bounds__(320) void k_final(const float* __restrict__ mu_g, const float* __restrict__ lv_g,
                                               const float* __restrict__ eps, float* __restrict__ out) {
    int g = blockIdx.x, c = threadIdx.x;
    if (c >= 300) return;
    out[g * 300 + c] = mu_g[g * 300 + c] + expf(0.5f * lv_g[g * 300 + c]) * eps[g * 300 + c];
}

extern "C" void kernel_launch(void* const* d_in, const int* in_sizes, int n_in,
                              void* d_out, int out_size, void* d_ws, size_t ws_size,
                              hipStream_t stream) {
    float* outp = (float*)d_out;

    const size_t NEED = 199500000ull;   // exact carve = 199,429,120 B; ws proven >= 200,000,000
    if (ws_size < NEED) {
        k_zerof<<<(out_size + 255) / 256, 256, 0, stream>>>(outp, out_size);
        return;
    }

    const float* x   = (const float*)d_in[0];
    const float* ea  = (const float*)d_in[1];
    const float* wat = (const float*)d_in[2];
    const float* eps = (const float*)d_in[3];
    const int* srcH  = (const int*)d_in[4];
    const int* dstH  = (const int*)d_in[5];
    const int* batch = (const int*)d_in[6];
    const float* w_t_lin  = (const float*)d_in[7];
    const float* b_t_lin  = (const float*)d_in[8];
    const float* w_t_mp   = (const float*)d_in[9];
    const float* b_t_mp   = (const float*)d_in[10];
    const float* w_t_au   = (const float*)d_in[11];
    const float* b_t_au   = (const float*)d_in[12];
    const float* w_mu_lin = (const float*)d_in[13];
    const float* b_mu_lin = (const float*)d_in[14];
    const float* w_mu_mp  = (const float*)d_in[15];
    const float* b_mu_mp  = (const float*)d_in[16];
    const float* w_mu_au  = (const float*)d_in[17];
    const float* b_mu_au  = (const float*)d_in[18];
    const float* w_lv_lin = (const float*)d_in[19];
    const float* b_lv_lin = (const float*)d_in[20];
    const float* w_lv_mp  = (const float*)d_in[21];
    const float* b_lv_mp  = (const float*)d_in[22];
    const float* w_lv_au  = (const float*)d_in[23];
    const float* b_lv_au  = (const float*)d_in[24];

    char* p = (char*)d_ws;
    auto alloc = [&](size_t nbytes) { char* q = p; p += (nbytes + 255) & ~(size_t)255; return q; };
    unsigned short* h   = (unsigned short*)alloc((size_t)NE * 300 * 2);   // 96 MB; tail reused as bf16 rows
    unsigned short* inc = (unsigned short*)alloc((size_t)NN * 300 * 2);   // 48 MB
    unsigned short* sh  = (unsigned short*)alloc((size_t)NN * 300 * 2);   // 48 MB
    const size_t MPU = (size_t)3 * 10 * 19 * 512;   // mp tables: 3 layers x 10kt x 19ct (ushorts)
    unsigned short* wh_mp = (unsigned short*)alloc(MPU * 2);
    unsigned short* wl_mp = (unsigned short*)alloc(MPU * 2);
    const size_t LAU = (size_t)29 * 19 * 512;       // lin+au tables (max 10+19 kt-tiles)
    unsigned short* wh_la = (unsigned short*)alloc(LAU * 2);
    unsigned short* wl_la = (unsigned short*)alloc(LAU * 2);
    float* mu_g = (float*)alloc((size_t)NG * 300 * 4);
    float* lv_g = (float*)alloc((size_t)NG * 300 * 4);
    int* deg    = (int*)alloc(NN * 4);               // reused as cursor (alias-safe)
    int* startA = (int*)alloc((NN + 1) * 4);
    int* elist  = (int*)alloc(NE * 4);
    int* degg   = (int*)alloc(NG * 4);
    int* gs     = (int*)alloc((NG + 1) * 4);

    // ---- CSR (incoming by dst) ----
    k_zeroi<<<(NN + 255) / 256, 256, 0, stream>>>(deg, NN);
    k_hist<<<(NE + 255) / 256, 256, 0, stream>>>(srcH, dstH, deg);
    k_scan_n<<<1, 1024, 0, stream>>>(deg, startA, deg, NN);
    k_fill<<<(NE + 255) / 256, 256, 0, stream>>>(srcH, dstH, deg, elist);
    // ---- graph-CSR over sorted batch ----
    k_zeroi<<<(NG + 255) / 256, 256, 0, stream>>>(degg, NG);
    k_histg<<<(NN + 255) / 256, 256, 0, stream>>>(batch, degg);
    k_scan_n<<<1, 1024, 0, stream>>>(degg, gs, (int*)nullptr, NG);

    const int SSG = (NN * 75 + 255) / 256;
    const size_t MP_L = (size_t)10 * 19 * 512;      // ushorts per mp layer
    unsigned short* rows = h;                        // bf16 rows alias (h dead at that point)
    auto wsplit = [&](const float* W, int K, int nkt, unsigned short* whi, unsigned short* wlo) {
        k_wsplit_g<<<(nkt * 19 * 64 + 255) / 256, 256, 0, stream>>>(W, K, nkt, whi, wlo);
    };

    // ================= conv t =================
    for (int i = 0; i < 3; ++i)
        wsplit(w_t_mp + i * 90000, 300, 10, wh_mp + i * MP_L, wl_mp + i * MP_L);
    wsplit(w_t_lin, 147, 5, wh_la, wl_la);
    const size_t AU_T = (size_t)5 * 19 * 512;
    wsplit(w_t_au, 433, 14, wh_la + AU_T, wl_la + AU_T);
    k_lin_mfma<133, float><<<NE / 32, 256, 0, stream>>>(x, ea, srcH, dstH, wh_la, wl_la, b_t_lin, h);
    for (int i = 0; i < 3; ++i) {
        k_segsum2<<<SSG, 256, 0, stream>>>(h, elist, startA, inc);
        k_mp_mfma<<<HALF / 16, 256, 0, stream>>>(h, inc, srcH, dstH,
                                                 wh_mp + i * MP_L, wl_mp + i * MP_L, b_t_mp + i * 300);
    }
    k_segsum2<<<SSG, 256, 0, stream>>>(h, elist, startA, inc);
    k_au_mfma<133, float, true><<<NN / 16, 256, 0, stream>>>(x, inc, wh_la + AU_T, wl_la + AU_T, b_t_au, sh);

    // ================= conv mu =================
    for (int i = 0; i < 3; ++i)
        wsplit(w_mu_mp + i * 90000, 300, 10, wh_mp + i * MP_L, wl_mp + i * MP_L);
    wsplit(w_mu_lin, 314, 10, wh_la, wl_la);
    const size_t AU_MU = (size_t)10 * 19 * 512;
    wsplit(w_mu_au, 600, 19, wh_la + AU_MU, wl_la + AU_MU);
    k_lin_mfma<300, unsigned short><<<NE / 32, 256, 0, stream>>>(sh, ea, srcH, dstH, wh_la, wl_la, b_mu_lin, h);
    for (int i = 0; i < 3; ++i) {
        k_segsum2<<<SSG, 256, 0, stream>>>(h, elist, startA, inc);
        k_mp_mfma<<<HALF / 16, 256, 0, stream>>>(h, inc, srcH, dstH,
                                                 wh_mp + i * MP_L, wl_mp + i * MP_L, b_mu_mp + i * 300);
    }
    k_segsum2<<<SSG, 256, 0, stream>>>(h, elist, startA, inc);
    k_au_mfma<300, unsigned short, false><<<NN / 16, 256, 0, stream>>>(sh, inc, wh_la + AU_MU, wl_la + AU_MU, b_mu_au, rows);
    k_pool<<<NG, 320, 0, stream>>>(rows, wat, gs, mu_g);

    // ================= conv lv =================
    for (int i = 0; i < 3; ++i)
        wsplit(w_lv_mp + i * 90000, 300, 10, wh_mp + i * MP_L, wl_mp + i * MP_L);
    wsplit(w_lv_lin, 314, 10, wh_la, wl_la);
    wsplit(w_lv_au, 600, 19, wh_la + AU_MU, wl_la + AU_MU);
    k_lin_mfma<300, unsigned short><<<NE / 32, 256, 0, stream>>>(sh, ea, srcH, dstH, wh_la, wl_la, b_lv_lin, h);
    for (int i = 0; i < 3; ++i) {
        k_segsum2<<<SSG, 256, 0, stream>>>(h, elist, startA, inc);
        k_mp_mfma<<<HALF / 16, 256, 0, stream>>>(h, inc, srcH, dstH,
                                                 wh_mp + i * MP_L, wl_mp + i * MP_L, b_lv_mp + i * 300);
    }
    k_segsum2<<<SSG, 256, 0, stream>>>(h, elist, startA, inc);
    k_au_mfma<300, unsigned short, false><<<NN / 16, 256, 0, stream>>>(sh, inc, wh_la + AU_MU, wl_la + AU_MU, b_lv_au, rows);
    k_pool<<<NG, 320, 0, stream>>>(rows, wat, gs, lv_g);

    // ---- reparam ----
    k_final<<<NG, 320, 0, stream>>>(mu_g, lv_g, eps, outp);
}